// Round 11
// baseline (148.041 us; speedup 1.0000x reference)
//
#include <hip/hip_runtime.h>
#include <float.h>
#include <math.h>

// Problem constants (fixed shapes from setup_inputs)
constexpr int B = 8, N1 = 400, N2 = 64, NP = N1 + N2, F = 54, C = 128;
constexpr int FP = 56;        // F padded for WtT rows (14 float4)
constexpr int FR = 64;        // feats row stride (floats), 256B float4-aligned
constexpr int RR = 40;        // lattice size after slicing
constexpr int RG = 41;        // scatter grid (includes dump cell at 40,40,40)
constexpr int VOX = RR*RR*RR; // 64000
constexpr int MAXOCC = NP;            // max occupied voxels per batch
constexpr int MAXACT = NP * 27;       // max multi voxels per batch
constexpr int NBG = (VOX/64) * (C/16);     // 8000 background partials
constexpr int PCHUNK = 16;            // pairs per S-block
constexpr int NCHUNK = 32;            // chunks per (b,sten) bucket (27*32*16 = 13824 >= 464*27)
constexpr int SBLK2 = 27*NCHUNK;      // 864 S-blocks per batch
constexpr int MBLK = 384;             // M-blocks per batch
constexpr int BSR = 16384;            // bsum region per batch (singles [0,864), multi 1024+)
constexpr int PPS = 512;              // padded s-range per (b,k) in k_compact
constexpr int CPB = 54;               // compact blocks per batch (27*512/256)

constexpr size_t align256(size_t x) { return (x + 255) & ~(size_t)255; }

// Workspace layout — 0xFF-init grids contiguous, then 0x00-init region contiguous
constexpr size_t OFF_SUB   = 0;                                   // B*3 f32
constexpr size_t OFF_WIN   = align256(OFF_SUB  + (size_t)B*3*4);  // B*41^3 i32   (0xFF)
constexpr size_t SZ_WIN    = (size_t)B*RG*RG*RG*4;
constexpr size_t OFF_SLOT  = align256(OFF_WIN  + SZ_WIN);         // B*40^3 i32   (0xFF)
constexpr size_t SZ_SLOT   = (size_t)B*VOX*4;
constexpr size_t OFF_AFST  = align256(OFF_SLOT + SZ_SLOT);        // B*40^3 u32   (0xFF)
constexpr size_t FF_END    = OFF_AFST + SZ_SLOT;
constexpr size_t OFF_ACNTG = align256(FF_END);                    // B*40^3 i32   (0x00)
constexpr size_t OFF_CNTS  = align256(OFF_ACNTG+ SZ_SLOT);        // B*16 i32     (0x00)
constexpr size_t OFF_BCNT  = align256(OFF_CNTS + (size_t)B*16*4); // 27*B*16 i32  (0x00)
constexpr size_t SZ_BCNT   = (size_t)B*27*16*4;
constexpr size_t OFF_FEAT  = align256(OFF_BCNT + SZ_BCNT);        // B*MAXOCC*FR f32 (0x00, padded rows)
constexpr size_t Z_END     = OFF_FEAT + (size_t)B*MAXOCC*FR*4;
constexpr size_t OFF_OCC   = align256(Z_END);                     // B*MAXOCC i32
constexpr size_t OFF_WT    = align256(OFF_OCC  + (size_t)B*MAXOCC*4);   // 27*F*C f32
constexpr size_t OFF_WTT   = align256(OFF_WT   + (size_t)27*F*C*4);     // 27*C*FP f32
constexpr size_t OFF_BG    = align256(OFF_WTT  + (size_t)27*C*FP*4);    // NBG f32
constexpr size_t OFF_SBUK  = align256(OFF_BG   + (size_t)NBG*4);        // B*27*MAXOCC int2
constexpr size_t OFF_MLST  = align256(OFF_SBUK + (size_t)B*27*MAXOCC*8);// B*MAXACT int2
constexpr size_t OFF_BSUM  = align256(OFF_MLST + (size_t)B*MAXACT*8);   // B*BSR f32
constexpr size_t OFF_FCT   = align256(OFF_BSUM + (size_t)B*BSR*4);      // VOX*C f32
constexpr size_t OFF_END   = OFF_FCT + (size_t)VOX*C*4;

constexpr int WT_BLKS  = (27*F*C + 63)/64;     // Wt fill blocks
constexpr int WTT_BLKS = (27*C*FP + 63)/64;    // WtT fill blocks

// ---------------- K1: bbox + conv_w transposes ----------------
__global__ __launch_bounds__(64)
void k_init(const float* __restrict__ pos1, const float* __restrict__ valid1,
            float* __restrict__ sub, const float* __restrict__ conv_w,
            float* __restrict__ Wt, float* __restrict__ WtT) {
    if (blockIdx.x < B) {
        int b = blockIdx.x;
        int t = threadIdx.x;
        float bmax[3] = {-FLT_MAX, -FLT_MAX, -FLT_MAX};
        float bmin[3] = { FLT_MAX,  FLT_MAX,  FLT_MAX};
        for (int n = t; n < N1; n += 64) {
            float v = valid1[b*N1 + n];
            const float* pp = pos1 + ((size_t)b*N1 + n)*3;
            float p0 = pp[0]*v, p1 = pp[1]*v, p2 = pp[2]*v;
            float s = p0 + p1 + p2;
            bool nz = (s == 0.0f);
            float amax = nz ? -10000000000.0f : 0.0f;
            float amin = nz ?  10000000000.0f : 0.0f;
            bmax[0] = fmaxf(bmax[0], p0 + amax);
            bmax[1] = fmaxf(bmax[1], p1 + amax);
            bmax[2] = fmaxf(bmax[2], p2 + amax);
            bmin[0] = fminf(bmin[0], p0 + amin);
            bmin[1] = fminf(bmin[1], p1 + amin);
            bmin[2] = fminf(bmin[2], p2 + amin);
        }
        #pragma unroll
        for (int off = 32; off; off >>= 1) {
            #pragma unroll
            for (int d = 0; d < 3; d++) {
                bmax[d] = fmaxf(bmax[d], __shfl_xor(bmax[d], off));
                bmin[d] = fminf(bmin[d], __shfl_xor(bmin[d], off));
            }
        }
        if (t == 0) {
            #pragma unroll
            for (int d = 0; d < 3; d++)
                sub[b*3 + d] = bmin[d] + (bmax[d] - bmin[d]) / 2.0f;
        }
    } else if (blockIdx.x < B + WT_BLKS) {
        int g = (blockIdx.x - B)*64 + threadIdx.x;
        if (g < 27*F*C) {
            int o = g & (C-1);
            int rest = g >> 7;       // C==128
            int f = rest % F, s = rest / F;
            Wt[g] = conv_w[((size_t)o*F + f)*27 + s];
        }
    } else {
        int g = (blockIdx.x - B - WT_BLKS)*64 + threadIdx.x;
        if (g < 27*C*FP) {
            int f = g % FP;
            int rest = g / FP;       // s*C + c
            int c = rest & (C-1), s = rest >> 7;
            WtT[g] = (f < F) ? conv_w[((size_t)c*F + f)*27 + s] : 0.0f;
        }
    }
}

// helper: compute voxel index for global point n (n<N1 -> pos1 else pos2)
__device__ inline void point_idx(const float* pos1, const float* valid1,
                                 const float* pos2, const float* valid2,
                                 const float* sub, int b, int n,
                                 int& ix, int& iy, int& iz, bool& inb, float& vout) {
    float px, py, pz, v;
    if (n < N1) {
        v = valid1[b*N1 + n];
        const float* p = pos1 + ((size_t)b*N1 + n)*3;
        px = p[0]*v; py = p[1]*v; pz = p[2]*v;
    } else {
        int m = n - N1;
        v = valid2[b*N2 + m];
        const float* p = pos2 + ((size_t)b*N2 + m)*3;
        px = p[0]*v; py = p[1]*v; pz = p[2]*v;
    }
    const float* sb = sub + b*3;
    ix = (int)floorf((px - sb[0] + 10.0f) / 0.5f);
    iy = (int)floorf((py - sb[1] + 10.0f) / 0.5f);
    iz = (int)floorf((pz - sb[2] + 10.0f) / 0.5f);
    inb = (ix >= 0 && ix <= RR-1 && iy >= 0 && iy <= RR-1 && iz >= 0 && iz <= RR-1);
    vout = v;
}

// ---------------- K2: winner scatter (last-write-wins via atomicMax) ----------------
__global__ void k_scatter(const float* __restrict__ pos1, const float* __restrict__ valid1,
                          const float* __restrict__ pos2, const float* __restrict__ valid2,
                          const float* __restrict__ sub, int* __restrict__ winner) {
    int g = blockIdx.x*blockDim.x + threadIdx.x;
    if (g >= B*NP) return;
    int b = g / NP, n = g % NP;
    int ix, iy, iz; bool inb; float v;
    point_idx(pos1, valid1, pos2, valid2, sub, b, n, ix, iy, iz, inb, v);
    int x = inb ? ix : RR, y = inb ? iy : RR, z = inb ? iz : RR;
    int cell = (x*RG + y)*RG + z;
    atomicMax(&winner[(size_t)b*RG*RG*RG + cell], n);
}

// ---------------- K3: claim winners, compact occupied list + features (padded rows) ----------------
__global__ void k_claim(const float* __restrict__ pos1, const float* __restrict__ valid1,
                        const float* __restrict__ pos2, const float* __restrict__ valid2,
                        const float* __restrict__ h1, const float* __restrict__ h2,
                        const float* __restrict__ sub, const int* __restrict__ winner,
                        int* __restrict__ slotGrid, int* __restrict__ counts,
                        int* __restrict__ occCoords, float* __restrict__ feats) {
    int g = blockIdx.x*blockDim.x + threadIdx.x;
    if (g >= B*NP) return;
    int b = g / NP, n = g % NP;
    int ix, iy, iz; bool inb; float v;
    point_idx(pos1, valid1, pos2, valid2, sub, b, n, ix, iy, iz, inb, v);
    if (!inb) return;  // dump cell (40,40,40) is sliced off
    int cell = (ix*RG + iy)*RG + iz;
    if (winner[(size_t)b*RG*RG*RG + cell] != n) return;
    int slot = atomicAdd(&counts[b*16], 1);
    slotGrid[(size_t)b*VOX + (ix*RR + iy)*RR + iz] = slot;
    occCoords[b*MAXOCC + slot] = (ix << 12) | (iy << 6) | iz;
    const float* h = (n < N1) ? (h1 + ((size_t)b*N1 + n)*F)
                              : (h2 + ((size_t)b*N2 + (n - N1))*F);
    float* fo = feats + ((size_t)b*MAXOCC + slot)*FR;
    for (int f = 0; f < F; f++) fo[f] = h[f] * v;
    // fo[54..63] remain zero from the per-call memset
}

// ---------------- K4: dilate -> contributor count + deterministic owner (atomicMin) ----------------
__global__ void k_dilate(const int* __restrict__ counts, const int* __restrict__ occCoords,
                         int* __restrict__ actCnt, unsigned* __restrict__ actFirst) {
    int g = blockIdx.x*blockDim.x + threadIdx.x;
    if (g >= B*MAXOCC*27) return;
    int b = g / (MAXOCC*27);
    int rem = g % (MAXOCC*27);
    int sl = rem / 27, k = rem % 27;
    if (sl >= counts[b*16]) return;
    int pc = occCoords[b*MAXOCC + sl];
    int x = pc >> 12, y = (pc >> 6) & 63, z = pc & 63;
    int nx = x + k/9 - 1, ny = y + (k/3)%3 - 1, nz = z + k%3 - 1;
    if (nx < 0 || nx >= RR || ny < 0 || ny >= RR || nz < 0 || nz >= RR) return;
    size_t lin = (size_t)b*VOX + (nx*RR + ny)*RR + nz;
    atomicAdd(&actCnt[lin], 1);
    int sten = (2 - k/9)*9 + ((k/3)%3)*3 + (k%3);
    atomicMin(&actFirst[lin], ((unsigned)sl << 5) | (unsigned)sten);
}

// ---------------- shared compact body ----------------
__device__ inline void compact_body(int g,
               const int* __restrict__ counts, const int* __restrict__ occCoords,
               const int* __restrict__ actCnt, const unsigned* __restrict__ actFirst,
               int* __restrict__ countsW, int* __restrict__ bCnt,
               int2* __restrict__ sBuck, int2* __restrict__ mList, int lane) {
    int bucket = g / PPS;          // b*27 + k
    int s = g % PPS;
    int b = bucket / 27, k = bucket % 27;
    if (b >= B) return;
    int sten = (2 - k/9)*9 + ((k/3)%3)*3 + (k%3);  // wave-uniform (bijection of k)
    bool ownS = false, ownM = false; int pcOut = 0;
    if (s < counts[b*16]) {
        int pc = occCoords[b*MAXOCC + s];
        int x = pc >> 12, y = (pc >> 6) & 63, z = pc & 63;
        int x0 = x + k/9 - 1, y0 = y + (k/3)%3 - 1, z0 = z + k%3 - 1;
        if (x0 >= 0 && x0 < RR && y0 >= 0 && y0 < RR && z0 >= 0 && z0 < RR) {
            size_t lin = (size_t)b*VOX + (x0*RR + y0)*RR + z0;
            unsigned myid = ((unsigned)s << 5) | (unsigned)sten;
            if (actFirst[lin] == myid) {
                pcOut = (x0 << 12) | (y0 << 6) | z0;
                if (actCnt[lin] == 1) ownS = true; else ownM = true;
            }
        }
    }
    unsigned long long mS = __ballot(ownS);
    if (mS != 0ull) {
        int lead = __builtin_ctzll(mS);
        int base = 0;
        if (lane == lead) base = atomicAdd(&bCnt[(b*27 + sten)*16], __popcll(mS));
        base = __shfl(base, lead);
        if (ownS) {
            int rank = __popcll(mS & ((1ull << lane) - 1ull));
            sBuck[((size_t)(b*27 + sten))*MAXOCC + base + rank] = make_int2(pcOut, s);
        }
    }
    unsigned long long mM = __ballot(ownM);
    if (mM != 0ull) {
        int lead = __builtin_ctzll(mM);
        int base = 0;
        if (lane == lead) base = atomicAdd(&countsW[b*16 + 8], __popcll(mM));
        base = __shfl(base, lead);
        if (ownM) {
            int rank = __popcll(mM & ((1ull << lane) - 1ull));
            mList[(size_t)b*MAXACT + base + rank] = make_int2(pcOut, 0);
        }
    }
}

// ---------------- K5: standalone compact (fallback path) ----------------
__global__ __launch_bounds__(256)
void k_compact(const int* __restrict__ counts, const int* __restrict__ occCoords,
               const int* __restrict__ actCnt, const unsigned* __restrict__ actFirst,
               int* __restrict__ countsW, int* __restrict__ bCnt,
               int2* __restrict__ sBuck, int2* __restrict__ mList) {
    int g = blockIdx.x*256 + threadIdx.x;
    compact_body(g, counts, occCoords, actCnt, actFirst, countsW, bCnt, sBuck, mList,
                 threadIdx.x & 63);
}

// ---------------- K6: fused fc_w transpose + background partials + compact ----------------
// x < CPB: compact for batch y.  x >= CPB: transpose v-block (x-CPB), o-block y.
__global__ __launch_bounds__(256)
void k_fct_compact(const float* __restrict__ fc_w, const float* __restrict__ conv_b,
                   float* __restrict__ fcT, float* __restrict__ bgBlock,
                   const int* __restrict__ counts, const int* __restrict__ occCoords,
                   const int* __restrict__ actCnt, const unsigned* __restrict__ actFirst,
                   int* __restrict__ countsW, int* __restrict__ bCnt,
                   int2* __restrict__ sBuck, int2* __restrict__ mList) {
    if (blockIdx.x < CPB) {
        int g = ((int)blockIdx.y*CPB + blockIdx.x)*256 + threadIdx.x;
        compact_body(g, counts, occCoords, actCnt, actFirst, countsW, bCnt, sBuck, mList,
                     threadIdx.x & 63);
        return;
    }
    __shared__ float tile[16][65];
    __shared__ float sred[16][17];
    __shared__ float sredw[16];
    int v0 = (blockIdx.x - CPB) * 64;  // 1000 v-blocks
    int o0 = blockIdx.y * 16;          // 8 o-blocks
    int t = threadIdx.x;               // 256
    int tv = t & 63, to = t >> 6;
    #pragma unroll
    for (int oo = 0; oo < 16; oo += 4)
        tile[to + oo][tv] = fc_w[(size_t)(o0 + to + oo)*VOX + v0 + tv];
    __syncthreads();
    int to2 = t & 15, tv2 = t >> 4;
    float s = 0.0f;
    #pragma unroll
    for (int vv = 0; vv < 64; vv += 16) {
        float val = tile[to2][tv2 + vv];
        fcT[(size_t)(v0 + tv2 + vv)*C + o0 + to2] = val;
        s += val;
    }
    sred[to2][tv2] = s;
    __syncthreads();
    if (t < 16) {
        float tot = 0.0f;
        #pragma unroll
        for (int i = 0; i < 16; i++) tot += sred[t][i];
        sredw[t] = fmaxf(conv_b[o0 + t], 0.0f) * tot;
    }
    __syncthreads();
    if (t == 0) {
        float tot = 0.0f;
        #pragma unroll
        for (int i = 0; i < 16; i++) tot += sredw[i];
        bgBlock[blockIdx.y*1000 + (blockIdx.x - CPB)] = tot;
    }
}

// ---------------- K6b: fallback background when fcT doesn't fit ----------------
__global__ __launch_bounds__(256)
void k_bg_fb(const float* __restrict__ fc_w, const float* __restrict__ conv_b,
             float* __restrict__ bgBlock) {
    int o = blockIdx.x;  // 128
    int t = threadIdx.x; // 256
    float s = 0.0f;
    for (int v = t; v < VOX; v += 256) s += fc_w[(size_t)o*VOX + v];
    #pragma unroll
    for (int off = 32; off; off >>= 1) s += __shfl_xor(s, off);
    __shared__ float red4[4];
    if ((t & 63) == 0) red4[t >> 6] = s;
    __syncthreads();
    if (t == 0) bgBlock[o] = fmaxf(conv_b[o], 0.0f) * (red4[0] + red4[1] + red4[2] + red4[3]);
}

// ---------------- K7: fused sparse conv (S: x<SBLK2, M: rest); both LDS-light ----------------
__global__ __launch_bounds__(256)
void k_conv(const int* __restrict__ slotGrid, const float* __restrict__ feats,
            const int* __restrict__ counts, const int* __restrict__ bCnt,
            const int2* __restrict__ sBuck, const int2* __restrict__ mList,
            const float* __restrict__ Wt, const float* __restrict__ WtT,
            const float* __restrict__ conv_b, const float* __restrict__ fcT,
            const float* __restrict__ fc_w, int useT, float* __restrict__ bsum) {
    int b = blockIdx.y;
    int t = threadIdx.x;

    __shared__ float4 fl4[16*16];        // 4 KB: [pair][f4slot]
    __shared__ int   flatS[16];
    __shared__ int   slotS[16];
    __shared__ float red[4];

    if (blockIdx.x < SBLK2) {
        // ---------- singles: 16 pairs/block, 256 thr = 128 ch x 2 halves ----------
        int sten = blockIdx.x >> 5;      // NCHUNK == 32
        int chunk = blockIdx.x & 31;
        int ch = t & 127, ph = t >> 7;   // channel, pair-half (8 pairs each)
        int cnt = bCnt[(b*27 + sten)*16];
        int base = chunk*PCHUNK;
        if (base >= cnt) { if (t == 0) bsum[(size_t)b*BSR + blockIdx.x] = 0.0f; return; }
        int rem = min(PCHUNK, cnt - base);

        // weights early, NAMED registers (resist rematerialization)
        const float4* wrow = (const float4*)(WtT + ((size_t)sten*C + ch)*FP);
        float4 w00 = wrow[0],  w01 = wrow[1],  w02 = wrow[2],  w03 = wrow[3];
        float4 w04 = wrow[4],  w05 = wrow[5],  w06 = wrow[6],  w07 = wrow[7];
        float4 w08 = wrow[8],  w09 = wrow[9],  w10 = wrow[10], w11 = wrow[11];
        float4 w12 = wrow[12], w13 = wrow[13];

        if (t < 16) {
            if (t < rem) {
                int2 e = sBuck[((size_t)(b*27 + sten))*MAXOCC + base + t];
                int pc = e.x;
                int x0 = pc >> 12, y0 = (pc >> 6) & 63, z0 = pc & 63;
                flatS[t] = x0*1600 + (RR-1 - y0)*RR + (RR-1 - z0);
                slotS[t] = e.y;
            } else { flatS[t] = 0; slotS[t] = -1; }
        }
        __syncthreads();
        // stage: 256 lanes = 16 pairs x 16 float4, one round, coalesced + conflict-free
        {
            const float4* fb4 = (const float4*)(feats + (size_t)b*MAXOCC*FR);
            int p = t >> 4, jf = t & 15;
            int sl = slotS[p];
            fl4[t] = (sl >= 0) ? fb4[(size_t)sl*(FR/4) + jf]
                               : make_float4(0.f, 0.f, 0.f, 0.f);
        }
        __syncthreads();

        float acc[8];
        #pragma unroll
        for (int p = 0; p < 8; p++) acc[p] = 0.0f;
        int pb = ph*8;
        #define JSTEP(WQ, J)                                        \
        {   _Pragma("unroll")                                       \
            for (int p = 0; p < 8; p++) {                           \
                float4 u = fl4[(pb + p)*16 + (J)];                  \
                acc[p] = fmaf(u.x, WQ.x, acc[p]);                   \
                acc[p] = fmaf(u.y, WQ.y, acc[p]);                   \
                acc[p] = fmaf(u.z, WQ.z, acc[p]);                   \
                acc[p] = fmaf(u.w, WQ.w, acc[p]); } }
        JSTEP(w00,0)  JSTEP(w01,1)  JSTEP(w02,2)  JSTEP(w03,3)
        JSTEP(w04,4)  JSTEP(w05,5)  JSTEP(w06,6)  JSTEP(w07,7)
        JSTEP(w08,8)  JSTEP(w09,9)  JSTEP(w10,10) JSTEP(w11,11)
        JSTEP(w12,12) JSTEP(w13,13)
        #undef JSTEP

        float cb = conv_b[ch];
        float rb = fmaxf(cb, 0.0f);
        float ssum = 0.0f;
        #pragma unroll
        for (int p = 0; p < 8; p++) {
            float wf = useT ? fcT[(size_t)flatS[pb + p]*C + ch]
                            : fc_w[(size_t)ch*VOX + flatS[pb + p]];
            // padded pairs: acc=0 -> relu(cb)-relu(cb)=0
            ssum = fmaf(fmaxf(acc[p] + cb, 0.0f) - rb, wf, ssum);
        }
        #pragma unroll
        for (int off = 32; off; off >>= 1) ssum += __shfl_xor(ssum, off);
        if ((t & 63) == 0) red[t >> 6] = ssum;
        __syncthreads();
        if (t == 0)
            bsum[(size_t)b*BSR + blockIdx.x] = red[0] + red[1] + red[2] + red[3];
        return;
    }

    // ---------- multi: 1 wave/voxel, quad contributor streams, no LDS ----------
    int wave = (blockIdx.x - SBLK2)*4 + (t >> 6);
    int lane = t & 63;
    int cntM = counts[b*16 + 8];
    int nw = MBLK*4;
    float cb0 = conv_b[lane], cb1 = conv_b[lane + 64];
    float rb0 = fmaxf(cb0, 0.0f), rb1 = fmaxf(cb1, 0.0f);
    const float* fb = feats + (size_t)b*MAXOCC*FR;

    for (int i = wave; i < cntM; i += nw) {
        int pc = mList[(size_t)b*MAXACT + i].x;
        int x0 = pc >> 12, y0 = (pc >> 6) & 63, z0 = pc & 63;
        int flat = x0*1600 + (RR-1 - y0)*RR + (RR-1 - z0);
        float w0, w1;
        if (useT) {
            w0 = fcT[(size_t)flat*C + lane];
            w1 = fcT[(size_t)flat*C + lane + 64];
        } else {
            w0 = fc_w[(size_t)lane*VOX + flat];
            w1 = fc_w[(size_t)(lane + 64)*VOX + flat];
        }
        int sl = -1;
        if (lane < 27) {
            int dp = lane/9, dq = (lane/3)%3, dr = lane%3;
            int nx = x0 + dp - 1, ny = y0 + 1 - dq, nz = z0 + 1 - dr;
            if (nx >= 0 && nx < RR && ny >= 0 && ny < RR && nz >= 0 && nz < RR)
                sl = slotGrid[(size_t)b*VOX + (nx*RR + ny)*RR + nz];
        }
        unsigned long long mask = __ballot(sl >= 0);
        float acc0 = 0.0f, acc1 = 0.0f;
        while (mask) {
            int eA = __builtin_ctzll(mask); mask &= mask - 1;
            int eB = eA, eC = eA, eD = eA, n = 1;
            if (mask) { eB = __builtin_ctzll(mask); mask &= mask - 1; n = 2;
              if (mask) { eC = __builtin_ctzll(mask); mask &= mask - 1; n = 3;
                if (mask) { eD = __builtin_ctzll(mask); mask &= mask - 1; n = 4; } } }
            int slA = __shfl(sl, eA), slB = __shfl(sl, eB);
            int slC = __shfl(sl, eC), slD = __shfl(sl, eD);
            float v0 = 0.0f, v1 = 0.0f, v2 = 0.0f, v3 = 0.0f;
            if (lane < F) {
                v0 = fb[(size_t)slA*FR + lane];
                v1 = (n > 1) ? fb[(size_t)slB*FR + lane] : 0.0f;
                v2 = (n > 2) ? fb[(size_t)slC*FR + lane] : 0.0f;
                v3 = (n > 3) ? fb[(size_t)slD*FR + lane] : 0.0f;
            }
            const float* wpA = Wt + (size_t)eA*F*C;
            const float* wpB = Wt + (size_t)eB*F*C;
            const float* wpC = Wt + (size_t)eC*F*C;
            const float* wpD = Wt + (size_t)eD*F*C;
            #pragma unroll 6
            for (int f = 0; f < F; f++) {
                float fA = __shfl(v0, f), fB = __shfl(v1, f);
                float fC = __shfl(v2, f), fD = __shfl(v3, f);
                acc0 = fmaf(fA, wpA[f*C + lane],      acc0);
                acc1 = fmaf(fA, wpA[f*C + lane + 64], acc1);
                acc0 = fmaf(fB, wpB[f*C + lane],      acc0);
                acc1 = fmaf(fB, wpB[f*C + lane + 64], acc1);
                acc0 = fmaf(fC, wpC[f*C + lane],      acc0);
                acc1 = fmaf(fC, wpC[f*C + lane + 64], acc1);
                acc0 = fmaf(fD, wpD[f*C + lane],      acc0);
                acc1 = fmaf(fD, wpD[f*C + lane + 64], acc1);
            }
        }
        float o0 = fmaxf(acc0 + cb0, 0.0f) - rb0;
        float o1 = fmaxf(acc1 + cb1, 0.0f) - rb1;
        float s = fmaf(o0, w0, o1*w1);
        #pragma unroll
        for (int off = 32; off; off >>= 1) s += __shfl_xor(s, off);
        if (lane == 0) bsum[(size_t)b*BSR + 1024 + i] = s;
    }
}

// ---------------- K8: deterministic per-batch reduce + background + sigmoid ----------------
__global__ __launch_bounds__(1024)
void k_reduce(const float* __restrict__ bsum, const float* __restrict__ bgBlock,
              const float* __restrict__ fc_b, const int* __restrict__ counts,
              float* __restrict__ out) {
    int b = blockIdx.x;
    int t = threadIdx.x;  // 1024
    float s = 0.0f;
    for (int i = t; i < SBLK2; i += 1024) s += bsum[(size_t)b*BSR + i];
    int cntM = counts[b*16 + 8];
    for (int i = t; i < cntM; i += 1024) s += bsum[(size_t)b*BSR + 1024 + i];
    for (int i = t; i < NBG; i += 1024) s += bgBlock[i];
    #pragma unroll
    for (int off = 32; off; off >>= 1) s += __shfl_xor(s, off);
    __shared__ float red[16];
    if ((t & 63) == 0) red[t >> 6] = s;
    __syncthreads();
    if (t == 0) {
        float tot = fc_b[0];
        #pragma unroll
        for (int i = 0; i < 16; i++) tot += red[i];
        out[b] = 1.0f / (1.0f + expf(-tot));
    }
}

extern "C" void kernel_launch(void* const* d_in, const int* in_sizes, int n_in,
                              void* d_out, int out_size, void* d_ws, size_t ws_size,
                              hipStream_t stream) {
    const float* pos1   = (const float*)d_in[0];
    const float* pos2   = (const float*)d_in[1];
    const float* h1     = (const float*)d_in[2];
    const float* h2     = (const float*)d_in[3];
    const float* valid1 = (const float*)d_in[4];
    const float* valid2 = (const float*)d_in[5];
    const float* conv_w = (const float*)d_in[6];
    const float* conv_b = (const float*)d_in[7];
    const float* fc_w   = (const float*)d_in[8];
    const float* fc_b   = (const float*)d_in[9];
    float* out = (float*)d_out;

    char* ws = (char*)d_ws;
    float*    sub      = (float*)   (ws + OFF_SUB);
    int*      winner   = (int*)     (ws + OFF_WIN);
    int*      slotGrid = (int*)     (ws + OFF_SLOT);
    unsigned* actFirst = (unsigned*)(ws + OFF_AFST);
    int*      actCnt   = (int*)     (ws + OFF_ACNTG);
    int*      counts   = (int*)     (ws + OFF_CNTS);
    int*      bCnt     = (int*)     (ws + OFF_BCNT);
    float*    feats    = (float*)   (ws + OFF_FEAT);
    int*      occCoords= (int*)     (ws + OFF_OCC);
    float*    Wt       = (float*)   (ws + OFF_WT);
    float*    WtT      = (float*)   (ws + OFF_WTT);
    float*    bgBlock  = (float*)   (ws + OFF_BG);
    int2*     sBuck    = (int2*)    (ws + OFF_SBUK);
    int2*     mList    = (int2*)    (ws + OFF_MLST);
    float*    bsum     = (float*)   (ws + OFF_BSUM);
    float*    fcT      = (float*)   (ws + OFF_FCT);

    const int useT = (ws_size >= OFF_END) ? 1 : 0;

    // per-call re-init (harness does not re-poison between replays) — 2 fused memsets
    hipMemsetAsync(ws + OFF_WIN,   0xFF, FF_END - OFF_WIN,   stream);
    hipMemsetAsync(ws + OFF_ACNTG, 0x00, Z_END - OFF_ACNTG,  stream);

    k_init<<<B + WT_BLKS + WTT_BLKS, 64, 0, stream>>>(pos1, valid1, sub, conv_w, Wt, WtT);
    k_scatter<<<(B*NP + 255)/256, 256, 0, stream>>>(pos1, valid1, pos2, valid2, sub, winner);
    k_claim<<<(B*NP + 255)/256, 256, 0, stream>>>(pos1, valid1, pos2, valid2, h1, h2,
                                                  sub, winner, slotGrid, counts, occCoords, feats);
    k_dilate<<<(B*MAXOCC*27 + 255)/256, 256, 0, stream>>>(counts, occCoords, actCnt, actFirst);
    if (useT) {
        k_fct_compact<<<dim3(CPB + VOX/64, B), 256, 0, stream>>>(
            fc_w, conv_b, fcT, bgBlock,
            counts, occCoords, actCnt, actFirst, counts, bCnt, sBuck, mList);
    } else {
        k_compact<<<(B*27*PPS)/256, 256, 0, stream>>>(counts, occCoords, actCnt, actFirst,
                                                      counts, bCnt, sBuck, mList);
        hipMemsetAsync(bgBlock, 0x00, (size_t)NBG*4, stream);
        k_bg_fb<<<C, 256, 0, stream>>>(fc_w, conv_b, bgBlock);
    }
    k_conv<<<dim3(SBLK2 + MBLK, B), 256, 0, stream>>>(slotGrid, feats, counts, bCnt,
                                                      sBuck, mList, Wt, WtT, conv_b,
                                                      fcT, fc_w, useT, bsum);
    k_reduce<<<B, 1024, 0, stream>>>(bsum, bgBlock, fc_b, counts, out);
}

// Round 12
// 122.314 us; speedup vs baseline: 1.2103x; 1.2103x over previous
//
#include <hip/hip_runtime.h>
#include <float.h>
#include <math.h>

// Problem constants (fixed shapes from setup_inputs)
constexpr int B = 8, N1 = 400, N2 = 64, NP = N1 + N2, F = 54, C = 128;
constexpr int RR = 40;        // lattice size after slicing
constexpr int RG = 41;        // scatter grid (includes dump cell at 40,40,40)
constexpr int VOX = RR*RR*RR; // 64000
constexpr int MAXOCC = NP;            // max occupied voxels per batch
constexpr int MAXACT = NP * 27;       // max multi voxels per batch
constexpr int NBG = (VOX/64) * (C/16);     // 8000 background partials
constexpr int PCHUNK = 16;            // pairs per k_convS block
constexpr int NCHUNK = 32;            // chunks per (b,sten) bucket
constexpr int BSR = 16384;            // bsum region per batch (singles [0,864), multi 1024+)
constexpr int PPS = 512;              // padded s-range per (b,k) in k_compact
constexpr int CPB = 54;               // compact blocks per batch (27*512/256)

constexpr size_t align256(size_t x) { return (x + 255) & ~(size_t)255; }

// Workspace layout — 0xFF-init grids contiguous, then 0x00-init grids contiguous
constexpr size_t OFF_SUB   = 0;                                   // B*3 f32
constexpr size_t OFF_WIN   = align256(OFF_SUB  + (size_t)B*3*4);  // B*41^3 i32   (0xFF)
constexpr size_t SZ_WIN    = (size_t)B*RG*RG*RG*4;
constexpr size_t OFF_SLOT  = align256(OFF_WIN  + SZ_WIN);         // B*40^3 i32   (0xFF)
constexpr size_t SZ_SLOT   = (size_t)B*VOX*4;
constexpr size_t OFF_AFST  = align256(OFF_SLOT + SZ_SLOT);        // B*40^3 u32   (0xFF)
constexpr size_t FF_END    = OFF_AFST + SZ_SLOT;
constexpr size_t OFF_ACNTG = align256(FF_END);                    // B*40^3 i32   (0x00)
constexpr size_t OFF_CNTS  = align256(OFF_ACNTG+ SZ_SLOT);        // B*16 i32     (0x00)
constexpr size_t OFF_BCNT  = align256(OFF_CNTS + (size_t)B*16*4); // 27*B*16 i32  (0x00)
constexpr size_t SZ_BCNT   = (size_t)B*27*16*4;
constexpr size_t Z_END     = OFF_BCNT + SZ_BCNT;
constexpr size_t OFF_OCC   = align256(Z_END);                     // B*MAXOCC i32
constexpr size_t OFF_FEAT  = align256(OFF_OCC  + (size_t)B*MAXOCC*4); // B*MAXOCC*F f32
constexpr size_t OFF_WT    = align256(OFF_FEAT + (size_t)B*MAXOCC*F*4); // 27*F*C f32
constexpr size_t OFF_BG    = align256(OFF_WT   + (size_t)27*F*C*4);     // NBG f32
constexpr size_t OFF_SBUK  = align256(OFF_BG   + (size_t)NBG*4);        // B*27*MAXOCC int2
constexpr size_t OFF_MLST  = align256(OFF_SBUK + (size_t)B*27*MAXOCC*8);// B*MAXACT int2
constexpr size_t OFF_BSUM  = align256(OFF_MLST + (size_t)B*MAXACT*8);   // B*BSR f32
constexpr size_t OFF_FCT   = align256(OFF_BSUM + (size_t)B*BSR*4);      // VOX*C f32
constexpr size_t OFF_END   = OFF_FCT + (size_t)VOX*C*4;

constexpr int WT_BLKS = (27*F*C + 63)/64;

// ---------------- K1: bbox (blocks 0..B-1) + conv_w transpose (rest) ----------------
__global__ __launch_bounds__(64)
void k_init(const float* __restrict__ pos1, const float* __restrict__ valid1,
            float* __restrict__ sub, const float* __restrict__ conv_w,
            float* __restrict__ Wt) {
    if (blockIdx.x < B) {
        int b = blockIdx.x;
        int t = threadIdx.x;
        float bmax[3] = {-FLT_MAX, -FLT_MAX, -FLT_MAX};
        float bmin[3] = { FLT_MAX,  FLT_MAX,  FLT_MAX};
        for (int n = t; n < N1; n += 64) {
            float v = valid1[b*N1 + n];
            const float* pp = pos1 + ((size_t)b*N1 + n)*3;
            float p0 = pp[0]*v, p1 = pp[1]*v, p2 = pp[2]*v;
            float s = p0 + p1 + p2;
            bool nz = (s == 0.0f);
            float amax = nz ? -10000000000.0f : 0.0f;
            float amin = nz ?  10000000000.0f : 0.0f;
            bmax[0] = fmaxf(bmax[0], p0 + amax);
            bmax[1] = fmaxf(bmax[1], p1 + amax);
            bmax[2] = fmaxf(bmax[2], p2 + amax);
            bmin[0] = fminf(bmin[0], p0 + amin);
            bmin[1] = fminf(bmin[1], p1 + amin);
            bmin[2] = fminf(bmin[2], p2 + amin);
        }
        #pragma unroll
        for (int off = 32; off; off >>= 1) {
            #pragma unroll
            for (int d = 0; d < 3; d++) {
                bmax[d] = fmaxf(bmax[d], __shfl_xor(bmax[d], off));
                bmin[d] = fminf(bmin[d], __shfl_xor(bmin[d], off));
            }
        }
        if (t == 0) {
            #pragma unroll
            for (int d = 0; d < 3; d++)
                sub[b*3 + d] = bmin[d] + (bmax[d] - bmin[d]) / 2.0f;
        }
    } else {
        int g = (blockIdx.x - B)*64 + threadIdx.x;
        if (g < 27*F*C) {
            int o = g & (C-1);
            int rest = g >> 7;       // C==128
            int f = rest % F, s = rest / F;
            Wt[g] = conv_w[((size_t)o*F + f)*27 + s];
        }
    }
}

// helper: compute voxel index for global point n (n<N1 -> pos1 else pos2)
__device__ inline void point_idx(const float* pos1, const float* valid1,
                                 const float* pos2, const float* valid2,
                                 const float* sub, int b, int n,
                                 int& ix, int& iy, int& iz, bool& inb, float& vout) {
    float px, py, pz, v;
    if (n < N1) {
        v = valid1[b*N1 + n];
        const float* p = pos1 + ((size_t)b*N1 + n)*3;
        px = p[0]*v; py = p[1]*v; pz = p[2]*v;
    } else {
        int m = n - N1;
        v = valid2[b*N2 + m];
        const float* p = pos2 + ((size_t)b*N2 + m)*3;
        px = p[0]*v; py = p[1]*v; pz = p[2]*v;
    }
    const float* sb = sub + b*3;
    ix = (int)floorf((px - sb[0] + 10.0f) / 0.5f);
    iy = (int)floorf((py - sb[1] + 10.0f) / 0.5f);
    iz = (int)floorf((pz - sb[2] + 10.0f) / 0.5f);
    inb = (ix >= 0 && ix <= RR-1 && iy >= 0 && iy <= RR-1 && iz >= 0 && iz <= RR-1);
    vout = v;
}

// ---------------- K2: winner scatter (last-write-wins via atomicMax) ----------------
__global__ void k_scatter(const float* __restrict__ pos1, const float* __restrict__ valid1,
                          const float* __restrict__ pos2, const float* __restrict__ valid2,
                          const float* __restrict__ sub, int* __restrict__ winner) {
    int g = blockIdx.x*blockDim.x + threadIdx.x;
    if (g >= B*NP) return;
    int b = g / NP, n = g % NP;
    int ix, iy, iz; bool inb; float v;
    point_idx(pos1, valid1, pos2, valid2, sub, b, n, ix, iy, iz, inb, v);
    int x = inb ? ix : RR, y = inb ? iy : RR, z = inb ? iz : RR;
    int cell = (x*RG + y)*RG + z;
    atomicMax(&winner[(size_t)b*RG*RG*RG + cell], n);
}

// ---------------- K3: claim winners, compact occupied list + features ----------------
__global__ void k_claim(const float* __restrict__ pos1, const float* __restrict__ valid1,
                        const float* __restrict__ pos2, const float* __restrict__ valid2,
                        const float* __restrict__ h1, const float* __restrict__ h2,
                        const float* __restrict__ sub, const int* __restrict__ winner,
                        int* __restrict__ slotGrid, int* __restrict__ counts,
                        int* __restrict__ occCoords, float* __restrict__ feats) {
    int g = blockIdx.x*blockDim.x + threadIdx.x;
    if (g >= B*NP) return;
    int b = g / NP, n = g % NP;
    int ix, iy, iz; bool inb; float v;
    point_idx(pos1, valid1, pos2, valid2, sub, b, n, ix, iy, iz, inb, v);
    if (!inb) return;  // dump cell (40,40,40) is sliced off
    int cell = (ix*RG + iy)*RG + iz;
    if (winner[(size_t)b*RG*RG*RG + cell] != n) return;
    int slot = atomicAdd(&counts[b*16], 1);
    slotGrid[(size_t)b*VOX + (ix*RR + iy)*RR + iz] = slot;
    occCoords[b*MAXOCC + slot] = (ix << 12) | (iy << 6) | iz;
    const float* h = (n < N1) ? (h1 + ((size_t)b*N1 + n)*F)
                              : (h2 + ((size_t)b*N2 + (n - N1))*F);
    float* fo = feats + ((size_t)b*MAXOCC + slot)*F;
    for (int f = 0; f < F; f++) fo[f] = h[f] * v;
}

// ---------------- K4: dilate -> contributor count + deterministic owner (atomicMin) ----------------
__global__ void k_dilate(const int* __restrict__ counts, const int* __restrict__ occCoords,
                         int* __restrict__ actCnt, unsigned* __restrict__ actFirst) {
    int g = blockIdx.x*blockDim.x + threadIdx.x;
    if (g >= B*MAXOCC*27) return;
    int b = g / (MAXOCC*27);
    int rem = g % (MAXOCC*27);
    int sl = rem / 27, k = rem % 27;
    if (sl >= counts[b*16]) return;
    int pc = occCoords[b*MAXOCC + sl];
    int x = pc >> 12, y = (pc >> 6) & 63, z = pc & 63;
    int nx = x + k/9 - 1, ny = y + (k/3)%3 - 1, nz = z + k%3 - 1;
    if (nx < 0 || nx >= RR || ny < 0 || ny >= RR || nz < 0 || nz >= RR) return;
    size_t lin = (size_t)b*VOX + (nx*RR + ny)*RR + nz;
    atomicAdd(&actCnt[lin], 1);
    int sten = (2 - k/9)*9 + ((k/3)%3)*3 + (k%3);
    atomicMin(&actFirst[lin], ((unsigned)sl << 5) | (unsigned)sten);
}

// ---------------- shared compact body ----------------
__device__ inline void compact_body(int g,
               const int* __restrict__ counts, const int* __restrict__ occCoords,
               const int* __restrict__ actCnt, const unsigned* __restrict__ actFirst,
               int* __restrict__ countsW, int* __restrict__ bCnt,
               int2* __restrict__ sBuck, int2* __restrict__ mList, int lane) {
    int bucket = g / PPS;          // b*27 + k
    int s = g % PPS;
    int b = bucket / 27, k = bucket % 27;
    if (b >= B) return;
    int sten = (2 - k/9)*9 + ((k/3)%3)*3 + (k%3);  // wave-uniform (bijection of k)
    bool ownS = false, ownM = false; int pcOut = 0;
    if (s < counts[b*16]) {
        int pc = occCoords[b*MAXOCC + s];
        int x = pc >> 12, y = (pc >> 6) & 63, z = pc & 63;
        int x0 = x + k/9 - 1, y0 = y + (k/3)%3 - 1, z0 = z + k%3 - 1;
        if (x0 >= 0 && x0 < RR && y0 >= 0 && y0 < RR && z0 >= 0 && z0 < RR) {
            size_t lin = (size_t)b*VOX + (x0*RR + y0)*RR + z0;
            unsigned myid = ((unsigned)s << 5) | (unsigned)sten;
            if (actFirst[lin] == myid) {
                pcOut = (x0 << 12) | (y0 << 6) | z0;
                if (actCnt[lin] == 1) ownS = true; else ownM = true;
            }
        }
    }
    unsigned long long mS = __ballot(ownS);
    if (mS != 0ull) {
        int lead = __builtin_ctzll(mS);
        int base = 0;
        if (lane == lead) base = atomicAdd(&bCnt[(b*27 + sten)*16], __popcll(mS));
        base = __shfl(base, lead);
        if (ownS) {
            int rank = __popcll(mS & ((1ull << lane) - 1ull));
            sBuck[((size_t)(b*27 + sten))*MAXOCC + base + rank] = make_int2(pcOut, s);
        }
    }
    unsigned long long mM = __ballot(ownM);
    if (mM != 0ull) {
        int lead = __builtin_ctzll(mM);
        int base = 0;
        if (lane == lead) base = atomicAdd(&countsW[b*16 + 8], __popcll(mM));
        base = __shfl(base, lead);
        if (ownM) {
            int rank = __popcll(mM & ((1ull << lane) - 1ull));
            mList[(size_t)b*MAXACT + base + rank] = make_int2(pcOut, 0);
        }
    }
}

// ---------------- K5: standalone compact (fallback path) ----------------
__global__ __launch_bounds__(256)
void k_compact(const int* __restrict__ counts, const int* __restrict__ occCoords,
               const int* __restrict__ actCnt, const unsigned* __restrict__ actFirst,
               int* __restrict__ countsW, int* __restrict__ bCnt,
               int2* __restrict__ sBuck, int2* __restrict__ mList) {
    int g = blockIdx.x*256 + threadIdx.x;
    compact_body(g, counts, occCoords, actCnt, actFirst, countsW, bCnt, sBuck, mList,
                 threadIdx.x & 63);
}

// ---------------- K6: fused fc_w transpose + background partials + compact ----------------
__global__ __launch_bounds__(256)
void k_fct_compact(const float* __restrict__ fc_w, const float* __restrict__ conv_b,
                   float* __restrict__ fcT, float* __restrict__ bgBlock,
                   const int* __restrict__ counts, const int* __restrict__ occCoords,
                   const int* __restrict__ actCnt, const unsigned* __restrict__ actFirst,
                   int* __restrict__ countsW, int* __restrict__ bCnt,
                   int2* __restrict__ sBuck, int2* __restrict__ mList) {
    if (blockIdx.x < CPB) {
        int g = ((int)blockIdx.y*CPB + blockIdx.x)*256 + threadIdx.x;
        compact_body(g, counts, occCoords, actCnt, actFirst, countsW, bCnt, sBuck, mList,
                     threadIdx.x & 63);
        return;
    }
    __shared__ float tile[16][65];
    __shared__ float sred[16][17];
    __shared__ float sredw[16];
    int v0 = (blockIdx.x - CPB) * 64;  // 1000 v-blocks
    int o0 = blockIdx.y * 16;          // 8 o-blocks (B == C/16)
    int t = threadIdx.x;               // 256
    int tv = t & 63, to = t >> 6;
    #pragma unroll
    for (int oo = 0; oo < 16; oo += 4)
        tile[to + oo][tv] = fc_w[(size_t)(o0 + to + oo)*VOX + v0 + tv];
    __syncthreads();
    int to2 = t & 15, tv2 = t >> 4;
    float s = 0.0f;
    #pragma unroll
    for (int vv = 0; vv < 64; vv += 16) {
        float val = tile[to2][tv2 + vv];
        fcT[(size_t)(v0 + tv2 + vv)*C + o0 + to2] = val;
        s += val;
    }
    sred[to2][tv2] = s;
    __syncthreads();
    if (t < 16) {
        float tot = 0.0f;
        #pragma unroll
        for (int i = 0; i < 16; i++) tot += sred[t][i];
        sredw[t] = fmaxf(conv_b[o0 + t], 0.0f) * tot;
    }
    __syncthreads();
    if (t == 0) {
        float tot = 0.0f;
        #pragma unroll
        for (int i = 0; i < 16; i++) tot += sredw[i];
        bgBlock[blockIdx.y*1000 + (blockIdx.x - CPB)] = tot;
    }
}

// ---------------- K6b: fallback background when fcT doesn't fit ----------------
__global__ __launch_bounds__(256)
void k_bg_fb(const float* __restrict__ fc_w, const float* __restrict__ conv_b,
             float* __restrict__ bgBlock) {
    int o = blockIdx.x;  // 128
    int t = threadIdx.x; // 256
    float s = 0.0f;
    for (int v = t; v < VOX; v += 256) s += fc_w[(size_t)o*VOX + v];
    #pragma unroll
    for (int off = 32; off; off >>= 1) s += __shfl_xor(s, off);
    __shared__ float red4[4];
    if ((t & 63) == 0) red4[t >> 6] = s;
    __syncthreads();
    if (t == 0) bgBlock[o] = fmaxf(conv_b[o], 0.0f) * (red4[0] + red4[1] + red4[2] + red4[3]);
}

// ---------------- K7: singles conv (r7 structure + fcT prefetch) ----------------
// block = (b, sten, chunk); thread t = channel; Wt slice read once per f for 16 pairs
__global__ __launch_bounds__(128)
void k_convS(const float* __restrict__ feats, const int* __restrict__ bCnt,
             const int2* __restrict__ sBuck, const float* __restrict__ Wt,
             const float* __restrict__ conv_b, const float* __restrict__ fcT,
             const float* __restrict__ fc_w, int useT, float* __restrict__ bsum) {
    int b = blockIdx.y;
    int sten = blockIdx.x >> 5;
    int chunk = blockIdx.x & 31;
    int t = threadIdx.x;  // 128 = channels
    int idxOut = sten*NCHUNK + chunk;
    int cnt = bCnt[(b*27 + sten)*16];
    int base = chunk*PCHUNK;
    if (base >= cnt) { if (t == 0) bsum[(size_t)b*BSR + idxOut] = 0.0f; return; }
    int rem = min(PCHUNK, cnt - base);

    __shared__ float fLDS[54][20];   // stride 20 floats (80B, 16B-aligned rows)
    __shared__ int   flatS[16];
    __shared__ int   slotS[16];
    __shared__ float red[2];

    if (t < 16) {
        if (t < rem) {
            int2 e = sBuck[((size_t)(b*27 + sten))*MAXOCC + base + t];
            int pc = e.x;
            int x0 = pc >> 12, y0 = (pc >> 6) & 63, z0 = pc & 63;
            flatS[t] = x0*1600 + (RR-1 - y0)*RR + (RR-1 - z0);
            slotS[t] = e.y;
        } else { flatS[t] = 0; slotS[t] = -1; }
    }
    __syncthreads();

    // T14-style prefetch: issue the 16 scattered fc-weight loads NOW so their
    // ~900cy HBM latency hides under feature staging + the 54-iter f-loop.
    float wf[16];
    #pragma unroll
    for (int p = 0; p < 16; p++)
        wf[p] = useT ? fcT[(size_t)flatS[p]*C + t]
                     : fc_w[(size_t)t*VOX + flatS[p]];

    for (int idx = t; idx < PCHUNK*F; idx += 128) {
        int p = idx / F, f = idx - p*F;
        int sl = slotS[p];
        fLDS[f][p] = (sl >= 0) ? feats[((size_t)b*MAXOCC + sl)*F + f] : 0.0f;
    }
    __syncthreads();

    const float* wv = Wt + (size_t)sten*F*C + t;
    float acc[16];
    #pragma unroll
    for (int p = 0; p < 16; p++) acc[p] = 0.0f;
    #pragma unroll 3
    for (int f = 0; f < F; f++) {
        float w = wv[(size_t)f*C];
        float4 a = *(const float4*)&fLDS[f][0];
        float4 q = *(const float4*)&fLDS[f][4];
        float4 c = *(const float4*)&fLDS[f][8];
        float4 d = *(const float4*)&fLDS[f][12];
        acc[0]  = fmaf(a.x, w, acc[0]);  acc[1]  = fmaf(a.y, w, acc[1]);
        acc[2]  = fmaf(a.z, w, acc[2]);  acc[3]  = fmaf(a.w, w, acc[3]);
        acc[4]  = fmaf(q.x, w, acc[4]);  acc[5]  = fmaf(q.y, w, acc[5]);
        acc[6]  = fmaf(q.z, w, acc[6]);  acc[7]  = fmaf(q.w, w, acc[7]);
        acc[8]  = fmaf(c.x, w, acc[8]);  acc[9]  = fmaf(c.y, w, acc[9]);
        acc[10] = fmaf(c.z, w, acc[10]); acc[11] = fmaf(c.w, w, acc[11]);
        acc[12] = fmaf(d.x, w, acc[12]); acc[13] = fmaf(d.y, w, acc[13]);
        acc[14] = fmaf(d.z, w, acc[14]); acc[15] = fmaf(d.w, w, acc[15]);
    }
    float cb = conv_b[t];
    float rb = fmaxf(cb, 0.0f);
    float ssum = 0.0f;
    #pragma unroll
    for (int p = 0; p < 16; p++) {
        if (p < rem) {
            float outv = fmaxf(acc[p] + cb, 0.0f) - rb;
            ssum = fmaf(outv, wf[p], ssum);
        }
    }
    #pragma unroll
    for (int off = 32; off; off >>= 1) ssum += __shfl_xor(ssum, off);
    if ((t & 63) == 0) red[t >> 6] = ssum;
    __syncthreads();
    if (t == 0) bsum[(size_t)b*BSR + idxOut] = red[0] + red[1];
}

// ---------------- K8: multi conv — 1 wave/voxel, paired shuffle-broadcast (r7) ----------------
__global__ __launch_bounds__(256)
void k_convM(const int* __restrict__ slotGrid, const float* __restrict__ feats,
             const int* __restrict__ counts, const int2* __restrict__ mList,
             const float* __restrict__ Wt, const float* __restrict__ conv_b,
             const float* __restrict__ fcT, const float* __restrict__ fc_w, int useT,
             float* __restrict__ bsum) {
    int b = blockIdx.y;
    int wave = blockIdx.x*4 + (threadIdx.x >> 6);
    int lane = threadIdx.x & 63;
    int cntM = counts[b*16 + 8];
    int nw = gridDim.x*4;
    float cb0 = conv_b[lane], cb1 = conv_b[lane + 64];
    float rb0 = fmaxf(cb0, 0.0f), rb1 = fmaxf(cb1, 0.0f);

    for (int i = wave; i < cntM; i += nw) {
        int pc = mList[(size_t)b*MAXACT + i].x;
        int x0 = pc >> 12, y0 = (pc >> 6) & 63, z0 = pc & 63;
        // fc weights early (independent of acc chain)
        int flat = x0*1600 + (RR-1 - y0)*RR + (RR-1 - z0);
        float w0, w1;
        if (useT) {
            w0 = fcT[(size_t)flat*C + lane];
            w1 = fcT[(size_t)flat*C + lane + 64];
        } else {
            w0 = fc_w[(size_t)lane*VOX + flat];
            w1 = fc_w[(size_t)(lane + 64)*VOX + flat];
        }
        int sl = -1;
        if (lane < 27) {
            int dp = lane/9, dq = (lane/3)%3, dr = lane%3;
            int nx = x0 + dp - 1, ny = y0 + 1 - dq, nz = z0 + 1 - dr;
            if (nx >= 0 && nx < RR && ny >= 0 && ny < RR && nz >= 0 && nz < RR)
                sl = slotGrid[(size_t)b*VOX + (nx*RR + ny)*RR + nz];
        }
        unsigned long long mask = __ballot(sl >= 0);
        float acc0 = 0.0f, acc1 = 0.0f;
        while (mask) {
            int eA = __builtin_ctzll(mask); mask &= mask - 1;
            int eB = eA;
            bool two = (mask != 0ull);
            if (two) { eB = __builtin_ctzll(mask); mask &= mask - 1; }
            int slA = __shfl(sl, eA);
            int slB = __shfl(sl, eB);
            float v0 = 0.0f, v1 = 0.0f;
            if (lane < F) {
                v0 = feats[((size_t)b*MAXOCC + slA)*F + lane];
                v1 = two ? feats[((size_t)b*MAXOCC + slB)*F + lane] : 0.0f;
            }
            const float* wpA = Wt + (size_t)eA*F*C;
            const float* wpB = Wt + (size_t)eB*F*C;
            #pragma unroll 9
            for (int f = 0; f < F; f++) {
                float fA = __shfl(v0, f);
                float fB = __shfl(v1, f);
                acc0 = fmaf(fA, wpA[f*C + lane],      acc0);
                acc1 = fmaf(fA, wpA[f*C + lane + 64], acc1);
                acc0 = fmaf(fB, wpB[f*C + lane],      acc0);
                acc1 = fmaf(fB, wpB[f*C + lane + 64], acc1);
            }
        }
        float o0 = fmaxf(acc0 + cb0, 0.0f) - rb0;
        float o1 = fmaxf(acc1 + cb1, 0.0f) - rb1;
        float s = fmaf(o0, w0, o1*w1);
        #pragma unroll
        for (int off = 32; off; off >>= 1) s += __shfl_xor(s, off);
        if (lane == 0) bsum[(size_t)b*BSR + 1024 + i] = s;
    }
}

// ---------------- K9: deterministic per-batch reduce + background + sigmoid ----------------
__global__ __launch_bounds__(1024)
void k_reduce(const float* __restrict__ bsum, const float* __restrict__ bgBlock,
              const float* __restrict__ fc_b, const int* __restrict__ counts,
              float* __restrict__ out) {
    int b = blockIdx.x;
    int t = threadIdx.x;  // 1024
    float s = 0.0f;
    for (int i = t; i < 27*NCHUNK; i += 1024) s += bsum[(size_t)b*BSR + i];
    int cntM = counts[b*16 + 8];
    for (int i = t; i < cntM; i += 1024) s += bsum[(size_t)b*BSR + 1024 + i];
    for (int i = t; i < NBG; i += 1024) s += bgBlock[i];
    #pragma unroll
    for (int off = 32; off; off >>= 1) s += __shfl_xor(s, off);
    __shared__ float red[16];
    if ((t & 63) == 0) red[t >> 6] = s;
    __syncthreads();
    if (t == 0) {
        float tot = fc_b[0];
        #pragma unroll
        for (int i = 0; i < 16; i++) tot += red[i];
        out[b] = 1.0f / (1.0f + expf(-tot));
    }
}

extern "C" void kernel_launch(void* const* d_in, const int* in_sizes, int n_in,
                              void* d_out, int out_size, void* d_ws, size_t ws_size,
                              hipStream_t stream) {
    const float* pos1   = (const float*)d_in[0];
    const float* pos2   = (const float*)d_in[1];
    const float* h1     = (const float*)d_in[2];
    const float* h2     = (const float*)d_in[3];
    const float* valid1 = (const float*)d_in[4];
    const float* valid2 = (const float*)d_in[5];
    const float* conv_w = (const float*)d_in[6];
    const float* conv_b = (const float*)d_in[7];
    const float* fc_w   = (const float*)d_in[8];
    const float* fc_b   = (const float*)d_in[9];
    float* out = (float*)d_out;

    char* ws = (char*)d_ws;
    float*    sub      = (float*)   (ws + OFF_SUB);
    int*      winner   = (int*)     (ws + OFF_WIN);
    int*      slotGrid = (int*)     (ws + OFF_SLOT);
    unsigned* actFirst = (unsigned*)(ws + OFF_AFST);
    int*      actCnt   = (int*)     (ws + OFF_ACNTG);
    int*      counts   = (int*)     (ws + OFF_CNTS);
    int*      bCnt     = (int*)     (ws + OFF_BCNT);
    int*      occCoords= (int*)     (ws + OFF_OCC);
    float*    feats    = (float*)   (ws + OFF_FEAT);
    float*    Wt       = (float*)   (ws + OFF_WT);
    float*    bgBlock  = (float*)   (ws + OFF_BG);
    int2*     sBuck    = (int2*)    (ws + OFF_SBUK);
    int2*     mList    = (int2*)    (ws + OFF_MLST);
    float*    bsum     = (float*)   (ws + OFF_BSUM);
    float*    fcT      = (float*)   (ws + OFF_FCT);

    const int useT = (ws_size >= OFF_END) ? 1 : 0;

    // per-call re-init (harness does not re-poison between replays) — 2 fused memsets
    hipMemsetAsync(ws + OFF_WIN,   0xFF, FF_END - OFF_WIN,   stream);
    hipMemsetAsync(ws + OFF_ACNTG, 0x00, Z_END - OFF_ACNTG,  stream);

    k_init<<<B + WT_BLKS, 64, 0, stream>>>(pos1, valid1, sub, conv_w, Wt);
    k_scatter<<<(B*NP + 255)/256, 256, 0, stream>>>(pos1, valid1, pos2, valid2, sub, winner);
    k_claim<<<(B*NP + 255)/256, 256, 0, stream>>>(pos1, valid1, pos2, valid2, h1, h2,
                                                  sub, winner, slotGrid, counts, occCoords, feats);
    k_dilate<<<(B*MAXOCC*27 + 255)/256, 256, 0, stream>>>(counts, occCoords, actCnt, actFirst);
    if (useT) {
        k_fct_compact<<<dim3(CPB + VOX/64, B), 256, 0, stream>>>(
            fc_w, conv_b, fcT, bgBlock,
            counts, occCoords, actCnt, actFirst, counts, bCnt, sBuck, mList);
    } else {
        k_compact<<<(B*27*PPS)/256, 256, 0, stream>>>(counts, occCoords, actCnt, actFirst,
                                                      counts, bCnt, sBuck, mList);
        hipMemsetAsync(bgBlock, 0x00, (size_t)NBG*4, stream);
        k_bg_fb<<<C, 256, 0, stream>>>(fc_w, conv_b, bgBlock);
    }
    k_convS<<<dim3(27*NCHUNK, B), 128, 0, stream>>>(feats, bCnt, sBuck, Wt, conv_b,
                                                    fcT, fc_w, useT, bsum);
    k_convM<<<dim3(512, B), 256, 0, stream>>>(slotGrid, feats, counts, mList,
                                              Wt, conv_b, fcT, fc_w, useT, bsum);
    k_reduce<<<B, 1024, 0, stream>>>(bsum, bgBlock, fc_b, counts, out);
}

// Round 13
// 122.232 us; speedup vs baseline: 1.2111x; 1.0007x over previous
//
#include <hip/hip_runtime.h>
#include <float.h>
#include <math.h>

// Problem constants (fixed shapes from setup_inputs)
constexpr int B = 8, N1 = 400, N2 = 64, NP = N1 + N2, F = 54, C = 128;
constexpr int RR = 40;        // lattice size after slicing
constexpr int RG = 41;        // scatter grid (includes dump cell at 40,40,40)
constexpr int VOX = RR*RR*RR; // 64000
constexpr int MAXOCC = NP;            // max occupied voxels per batch
constexpr int MAXACT = NP * 27;       // max multi voxels per batch
constexpr int NBG = (VOX/64) * (C/16);     // 8000 background partials
constexpr int PCHUNK = 16;            // pairs per k_convS block
constexpr int NCHUNK = 32;            // chunks per (b,sten) bucket
constexpr int BSR = 16384;            // bsum region per batch (singles [0,864), multi 1024+)
constexpr int PPS = 512;              // padded s-range per (b,k) in k_compact
constexpr int CPB = 54;               // compact blocks per batch (27*512/256)

constexpr size_t align256(size_t x) { return (x + 255) & ~(size_t)255; }

// Workspace layout — 0xFF-init grids contiguous, then 0x00-init grids contiguous
constexpr size_t OFF_SUB   = 0;                                   // B*3 f32
constexpr size_t OFF_WIN   = align256(OFF_SUB  + (size_t)B*3*4);  // B*41^3 i32   (0xFF)
constexpr size_t SZ_WIN    = (size_t)B*RG*RG*RG*4;
constexpr size_t OFF_SLOT  = align256(OFF_WIN  + SZ_WIN);         // B*40^3 i32   (0xFF)
constexpr size_t SZ_SLOT   = (size_t)B*VOX*4;
constexpr size_t OFF_AFST  = align256(OFF_SLOT + SZ_SLOT);        // B*40^3 u32   (0xFF)
constexpr size_t FF_END    = OFF_AFST + SZ_SLOT;
constexpr size_t OFF_ACNTG = align256(FF_END);                    // B*40^3 i32   (0x00)
constexpr size_t OFF_CNTS  = align256(OFF_ACNTG+ SZ_SLOT);        // B*16 i32     (0x00)
constexpr size_t OFF_BCNT  = align256(OFF_CNTS + (size_t)B*16*4); // 27*B*16 i32  (0x00)
constexpr size_t SZ_BCNT   = (size_t)B*27*16*4;
constexpr size_t Z_END     = OFF_BCNT + SZ_BCNT;
constexpr size_t OFF_OCC   = align256(Z_END);                     // B*MAXOCC i32
constexpr size_t OFF_FEAT  = align256(OFF_OCC  + (size_t)B*MAXOCC*4); // B*MAXOCC*F f32
constexpr size_t OFF_WT    = align256(OFF_FEAT + (size_t)B*MAXOCC*F*4); // 27*F*C f32
constexpr size_t OFF_BG    = align256(OFF_WT   + (size_t)27*F*C*4);     // NBG f32
constexpr size_t OFF_SBUK  = align256(OFF_BG   + (size_t)NBG*4);        // B*27*MAXOCC int2
constexpr size_t OFF_MLST  = align256(OFF_SBUK + (size_t)B*27*MAXOCC*8);// B*MAXACT int2
constexpr size_t OFF_BSUM  = align256(OFF_MLST + (size_t)B*MAXACT*8);   // B*BSR f32
constexpr size_t OFF_FCT   = align256(OFF_BSUM + (size_t)B*BSR*4);      // VOX*C f32
constexpr size_t OFF_END   = OFF_FCT + (size_t)VOX*C*4;

constexpr int WT_BLKS = (27*F*C + 63)/64;

// ---------------- K1: bbox (blocks 0..B-1) + conv_w transpose (rest) ----------------
__global__ __launch_bounds__(64)
void k_init(const float* __restrict__ pos1, const float* __restrict__ valid1,
            float* __restrict__ sub, const float* __restrict__ conv_w,
            float* __restrict__ Wt) {
    if (blockIdx.x < B) {
        int b = blockIdx.x;
        int t = threadIdx.x;
        float bmax[3] = {-FLT_MAX, -FLT_MAX, -FLT_MAX};
        float bmin[3] = { FLT_MAX,  FLT_MAX,  FLT_MAX};
        for (int n = t; n < N1; n += 64) {
            float v = valid1[b*N1 + n];
            const float* pp = pos1 + ((size_t)b*N1 + n)*3;
            float p0 = pp[0]*v, p1 = pp[1]*v, p2 = pp[2]*v;
            float s = p0 + p1 + p2;
            bool nz = (s == 0.0f);
            float amax = nz ? -10000000000.0f : 0.0f;
            float amin = nz ?  10000000000.0f : 0.0f;
            bmax[0] = fmaxf(bmax[0], p0 + amax);
            bmax[1] = fmaxf(bmax[1], p1 + amax);
            bmax[2] = fmaxf(bmax[2], p2 + amax);
            bmin[0] = fminf(bmin[0], p0 + amin);
            bmin[1] = fminf(bmin[1], p1 + amin);
            bmin[2] = fminf(bmin[2], p2 + amin);
        }
        #pragma unroll
        for (int off = 32; off; off >>= 1) {
            #pragma unroll
            for (int d = 0; d < 3; d++) {
                bmax[d] = fmaxf(bmax[d], __shfl_xor(bmax[d], off));
                bmin[d] = fminf(bmin[d], __shfl_xor(bmin[d], off));
            }
        }
        if (t == 0) {
            #pragma unroll
            for (int d = 0; d < 3; d++)
                sub[b*3 + d] = bmin[d] + (bmax[d] - bmin[d]) / 2.0f;
        }
    } else {
        int g = (blockIdx.x - B)*64 + threadIdx.x;
        if (g < 27*F*C) {
            int o = g & (C-1);
            int rest = g >> 7;       // C==128
            int f = rest % F, s = rest / F;
            Wt[g] = conv_w[((size_t)o*F + f)*27 + s];
        }
    }
}

// helper: compute voxel index for global point n (n<N1 -> pos1 else pos2)
__device__ inline void point_idx(const float* pos1, const float* valid1,
                                 const float* pos2, const float* valid2,
                                 const float* sub, int b, int n,
                                 int& ix, int& iy, int& iz, bool& inb, float& vout) {
    float px, py, pz, v;
    if (n < N1) {
        v = valid1[b*N1 + n];
        const float* p = pos1 + ((size_t)b*N1 + n)*3;
        px = p[0]*v; py = p[1]*v; pz = p[2]*v;
    } else {
        int m = n - N1;
        v = valid2[b*N2 + m];
        const float* p = pos2 + ((size_t)b*N2 + m)*3;
        px = p[0]*v; py = p[1]*v; pz = p[2]*v;
    }
    const float* sb = sub + b*3;
    ix = (int)floorf((px - sb[0] + 10.0f) / 0.5f);
    iy = (int)floorf((py - sb[1] + 10.0f) / 0.5f);
    iz = (int)floorf((pz - sb[2] + 10.0f) / 0.5f);
    inb = (ix >= 0 && ix <= RR-1 && iy >= 0 && iy <= RR-1 && iz >= 0 && iz <= RR-1);
    vout = v;
}

// ---------------- K2: winner scatter (last-write-wins via atomicMax) ----------------
__global__ void k_scatter(const float* __restrict__ pos1, const float* __restrict__ valid1,
                          const float* __restrict__ pos2, const float* __restrict__ valid2,
                          const float* __restrict__ sub, int* __restrict__ winner) {
    int g = blockIdx.x*blockDim.x + threadIdx.x;
    if (g >= B*NP) return;
    int b = g / NP, n = g % NP;
    int ix, iy, iz; bool inb; float v;
    point_idx(pos1, valid1, pos2, valid2, sub, b, n, ix, iy, iz, inb, v);
    int x = inb ? ix : RR, y = inb ? iy : RR, z = inb ? iz : RR;
    int cell = (x*RG + y)*RG + z;
    atomicMax(&winner[(size_t)b*RG*RG*RG + cell], n);
}

// ---------------- K3: claim winners, compact occupied list + features ----------------
__global__ void k_claim(const float* __restrict__ pos1, const float* __restrict__ valid1,
                        const float* __restrict__ pos2, const float* __restrict__ valid2,
                        const float* __restrict__ h1, const float* __restrict__ h2,
                        const float* __restrict__ sub, const int* __restrict__ winner,
                        int* __restrict__ slotGrid, int* __restrict__ counts,
                        int* __restrict__ occCoords, float* __restrict__ feats) {
    int g = blockIdx.x*blockDim.x + threadIdx.x;
    if (g >= B*NP) return;
    int b = g / NP, n = g % NP;
    int ix, iy, iz; bool inb; float v;
    point_idx(pos1, valid1, pos2, valid2, sub, b, n, ix, iy, iz, inb, v);
    if (!inb) return;  // dump cell (40,40,40) is sliced off
    int cell = (ix*RG + iy)*RG + iz;
    if (winner[(size_t)b*RG*RG*RG + cell] != n) return;
    int slot = atomicAdd(&counts[b*16], 1);
    slotGrid[(size_t)b*VOX + (ix*RR + iy)*RR + iz] = slot;
    occCoords[b*MAXOCC + slot] = (ix << 12) | (iy << 6) | iz;
    const float* h = (n < N1) ? (h1 + ((size_t)b*N1 + n)*F)
                              : (h2 + ((size_t)b*N2 + (n - N1))*F);
    float* fo = feats + ((size_t)b*MAXOCC + slot)*F;
    for (int f = 0; f < F; f++) fo[f] = h[f] * v;
}

// ---------------- K4: dilate -> contributor count + deterministic owner (atomicMin) ----------------
__global__ void k_dilate(const int* __restrict__ counts, const int* __restrict__ occCoords,
                         int* __restrict__ actCnt, unsigned* __restrict__ actFirst) {
    int g = blockIdx.x*blockDim.x + threadIdx.x;
    if (g >= B*MAXOCC*27) return;
    int b = g / (MAXOCC*27);
    int rem = g % (MAXOCC*27);
    int sl = rem / 27, k = rem % 27;
    if (sl >= counts[b*16]) return;
    int pc = occCoords[b*MAXOCC + sl];
    int x = pc >> 12, y = (pc >> 6) & 63, z = pc & 63;
    int nx = x + k/9 - 1, ny = y + (k/3)%3 - 1, nz = z + k%3 - 1;
    if (nx < 0 || nx >= RR || ny < 0 || ny >= RR || nz < 0 || nz >= RR) return;
    size_t lin = (size_t)b*VOX + (nx*RR + ny)*RR + nz;
    atomicAdd(&actCnt[lin], 1);
    int sten = (2 - k/9)*9 + ((k/3)%3)*3 + (k%3);
    atomicMin(&actFirst[lin], ((unsigned)sl << 5) | (unsigned)sten);
}

// ---------------- shared compact body ----------------
__device__ inline void compact_body(int g,
               const int* __restrict__ counts, const int* __restrict__ occCoords,
               const int* __restrict__ actCnt, const unsigned* __restrict__ actFirst,
               int* __restrict__ countsW, int* __restrict__ bCnt,
               int2* __restrict__ sBuck, int2* __restrict__ mList, int lane) {
    int bucket = g / PPS;          // b*27 + k
    int s = g % PPS;
    int b = bucket / 27, k = bucket % 27;
    if (b >= B) return;
    int sten = (2 - k/9)*9 + ((k/3)%3)*3 + (k%3);  // wave-uniform (bijection of k)
    bool ownS = false, ownM = false; int pcOut = 0;
    if (s < counts[b*16]) {
        int pc = occCoords[b*MAXOCC + s];
        int x = pc >> 12, y = (pc >> 6) & 63, z = pc & 63;
        int x0 = x + k/9 - 1, y0 = y + (k/3)%3 - 1, z0 = z + k%3 - 1;
        if (x0 >= 0 && x0 < RR && y0 >= 0 && y0 < RR && z0 >= 0 && z0 < RR) {
            size_t lin = (size_t)b*VOX + (x0*RR + y0)*RR + z0;
            unsigned myid = ((unsigned)s << 5) | (unsigned)sten;
            if (actFirst[lin] == myid) {
                pcOut = (x0 << 12) | (y0 << 6) | z0;
                if (actCnt[lin] == 1) ownS = true; else ownM = true;
            }
        }
    }
    unsigned long long mS = __ballot(ownS);
    if (mS != 0ull) {
        int lead = __builtin_ctzll(mS);
        int base = 0;
        if (lane == lead) base = atomicAdd(&bCnt[(b*27 + sten)*16], __popcll(mS));
        base = __shfl(base, lead);
        if (ownS) {
            int rank = __popcll(mS & ((1ull << lane) - 1ull));
            sBuck[((size_t)(b*27 + sten))*MAXOCC + base + rank] = make_int2(pcOut, s);
        }
    }
    unsigned long long mM = __ballot(ownM);
    if (mM != 0ull) {
        int lead = __builtin_ctzll(mM);
        int base = 0;
        if (lane == lead) base = atomicAdd(&countsW[b*16 + 8], __popcll(mM));
        base = __shfl(base, lead);
        if (ownM) {
            int rank = __popcll(mM & ((1ull << lane) - 1ull));
            mList[(size_t)b*MAXACT + base + rank] = make_int2(pcOut, 0);
        }
    }
}

// ---------------- K5: standalone compact (fallback path) ----------------
__global__ __launch_bounds__(256)
void k_compact(const int* __restrict__ counts, const int* __restrict__ occCoords,
               const int* __restrict__ actCnt, const unsigned* __restrict__ actFirst,
               int* __restrict__ countsW, int* __restrict__ bCnt,
               int2* __restrict__ sBuck, int2* __restrict__ mList) {
    int g = blockIdx.x*256 + threadIdx.x;
    compact_body(g, counts, occCoords, actCnt, actFirst, countsW, bCnt, sBuck, mList,
                 threadIdx.x & 63);
}

// ---------------- K6: fused fc_w transpose + background partials + compact ----------------
__global__ __launch_bounds__(256)
void k_fct_compact(const float* __restrict__ fc_w, const float* __restrict__ conv_b,
                   float* __restrict__ fcT, float* __restrict__ bgBlock,
                   const int* __restrict__ counts, const int* __restrict__ occCoords,
                   const int* __restrict__ actCnt, const unsigned* __restrict__ actFirst,
                   int* __restrict__ countsW, int* __restrict__ bCnt,
                   int2* __restrict__ sBuck, int2* __restrict__ mList) {
    if (blockIdx.x < CPB) {
        int g = ((int)blockIdx.y*CPB + blockIdx.x)*256 + threadIdx.x;
        compact_body(g, counts, occCoords, actCnt, actFirst, countsW, bCnt, sBuck, mList,
                     threadIdx.x & 63);
        return;
    }
    __shared__ float tile[16][65];
    __shared__ float sred[16][17];
    __shared__ float sredw[16];
    int v0 = (blockIdx.x - CPB) * 64;  // 1000 v-blocks
    int o0 = blockIdx.y * 16;          // 8 o-blocks (B == C/16)
    int t = threadIdx.x;               // 256
    int tv = t & 63, to = t >> 6;
    #pragma unroll
    for (int oo = 0; oo < 16; oo += 4)
        tile[to + oo][tv] = fc_w[(size_t)(o0 + to + oo)*VOX + v0 + tv];
    __syncthreads();
    int to2 = t & 15, tv2 = t >> 4;
    float s = 0.0f;
    #pragma unroll
    for (int vv = 0; vv < 64; vv += 16) {
        float val = tile[to2][tv2 + vv];
        fcT[(size_t)(v0 + tv2 + vv)*C + o0 + to2] = val;
        s += val;
    }
    sred[to2][tv2] = s;
    __syncthreads();
    if (t < 16) {
        float tot = 0.0f;
        #pragma unroll
        for (int i = 0; i < 16; i++) tot += sred[t][i];
        sredw[t] = fmaxf(conv_b[o0 + t], 0.0f) * tot;
    }
    __syncthreads();
    if (t == 0) {
        float tot = 0.0f;
        #pragma unroll
        for (int i = 0; i < 16; i++) tot += sredw[i];
        bgBlock[blockIdx.y*1000 + (blockIdx.x - CPB)] = tot;
    }
}

// ---------------- K6b: fallback background when fcT doesn't fit ----------------
__global__ __launch_bounds__(256)
void k_bg_fb(const float* __restrict__ fc_w, const float* __restrict__ conv_b,
             float* __restrict__ bgBlock) {
    int o = blockIdx.x;  // 128
    int t = threadIdx.x; // 256
    float s = 0.0f;
    for (int v = t; v < VOX; v += 256) s += fc_w[(size_t)o*VOX + v];
    #pragma unroll
    for (int off = 32; off; off >>= 1) s += __shfl_xor(s, off);
    __shared__ float red4[4];
    if ((t & 63) == 0) red4[t >> 6] = s;
    __syncthreads();
    if (t == 0) bgBlock[o] = fmaxf(conv_b[o], 0.0f) * (red4[0] + red4[1] + red4[2] + red4[3]);
}

// ---------------- K7: singles conv (r7 structure + fcT prefetch) ----------------
// block = (b, sten, chunk); thread t = channel; Wt slice read once per f for 16 pairs
__global__ __launch_bounds__(128)
void k_convS(const float* __restrict__ feats, const int* __restrict__ bCnt,
             const int2* __restrict__ sBuck, const float* __restrict__ Wt,
             const float* __restrict__ conv_b, const float* __restrict__ fcT,
             const float* __restrict__ fc_w, int useT, float* __restrict__ bsum) {
    int b = blockIdx.y;
    int sten = blockIdx.x >> 5;
    int chunk = blockIdx.x & 31;
    int t = threadIdx.x;  // 128 = channels
    int idxOut = sten*NCHUNK + chunk;
    int cnt = bCnt[(b*27 + sten)*16];
    int base = chunk*PCHUNK;
    if (base >= cnt) { if (t == 0) bsum[(size_t)b*BSR + idxOut] = 0.0f; return; }
    int rem = min(PCHUNK, cnt - base);

    __shared__ float fLDS[54][20];   // stride 20 floats (80B, 16B-aligned rows)
    __shared__ int   flatS[16];
    __shared__ int   slotS[16];
    __shared__ float red[2];

    if (t < 16) {
        if (t < rem) {
            int2 e = sBuck[((size_t)(b*27 + sten))*MAXOCC + base + t];
            int pc = e.x;
            int x0 = pc >> 12, y0 = (pc >> 6) & 63, z0 = pc & 63;
            flatS[t] = x0*1600 + (RR-1 - y0)*RR + (RR-1 - z0);
            slotS[t] = e.y;
        } else { flatS[t] = 0; slotS[t] = -1; }
    }
    __syncthreads();

    // T14-style prefetch: issue the 16 scattered fc-weight loads NOW so their
    // ~900cy HBM latency hides under feature staging + the 54-iter f-loop.
    float wf[16];
    #pragma unroll
    for (int p = 0; p < 16; p++)
        wf[p] = useT ? fcT[(size_t)flatS[p]*C + t]
                     : fc_w[(size_t)t*VOX + flatS[p]];

    for (int idx = t; idx < PCHUNK*F; idx += 128) {
        int p = idx / F, f = idx - p*F;
        int sl = slotS[p];
        fLDS[f][p] = (sl >= 0) ? feats[((size_t)b*MAXOCC + sl)*F + f] : 0.0f;
    }
    __syncthreads();

    const float* wv = Wt + (size_t)sten*F*C + t;
    float acc[16];
    #pragma unroll
    for (int p = 0; p < 16; p++) acc[p] = 0.0f;
    #pragma unroll 3
    for (int f = 0; f < F; f++) {
        float w = wv[(size_t)f*C];
        float4 a = *(const float4*)&fLDS[f][0];
        float4 q = *(const float4*)&fLDS[f][4];
        float4 c = *(const float4*)&fLDS[f][8];
        float4 d = *(const float4*)&fLDS[f][12];
        acc[0]  = fmaf(a.x, w, acc[0]);  acc[1]  = fmaf(a.y, w, acc[1]);
        acc[2]  = fmaf(a.z, w, acc[2]);  acc[3]  = fmaf(a.w, w, acc[3]);
        acc[4]  = fmaf(q.x, w, acc[4]);  acc[5]  = fmaf(q.y, w, acc[5]);
        acc[6]  = fmaf(q.z, w, acc[6]);  acc[7]  = fmaf(q.w, w, acc[7]);
        acc[8]  = fmaf(c.x, w, acc[8]);  acc[9]  = fmaf(c.y, w, acc[9]);
        acc[10] = fmaf(c.z, w, acc[10]); acc[11] = fmaf(c.w, w, acc[11]);
        acc[12] = fmaf(d.x, w, acc[12]); acc[13] = fmaf(d.y, w, acc[13]);
        acc[14] = fmaf(d.z, w, acc[14]); acc[15] = fmaf(d.w, w, acc[15]);
    }
    float cb = conv_b[t];
    float rb = fmaxf(cb, 0.0f);
    float ssum = 0.0f;
    #pragma unroll
    for (int p = 0; p < 16; p++) {
        if (p < rem) {
            float outv = fmaxf(acc[p] + cb, 0.0f) - rb;
            ssum = fmaf(outv, wf[p], ssum);
        }
    }
    #pragma unroll
    for (int off = 32; off; off >>= 1) ssum += __shfl_xor(ssum, off);
    if ((t & 63) == 0) red[t >> 6] = ssum;
    __syncthreads();
    if (t == 0) bsum[(size_t)b*BSR + idxOut] = red[0] + red[1];
}

// ---------------- K8: multi conv — 1 wave/voxel, paired shuffle-broadcast (r7) ----------------
__global__ __launch_bounds__(256)
void k_convM(const int* __restrict__ slotGrid, const float* __restrict__ feats,
             const int* __restrict__ counts, const int2* __restrict__ mList,
             const float* __restrict__ Wt, const float* __restrict__ conv_b,
             const float* __restrict__ fcT, const float* __restrict__ fc_w, int useT,
             float* __restrict__ bsum) {
    int b = blockIdx.y;
    int wave = blockIdx.x*4 + (threadIdx.x >> 6);
    int lane = threadIdx.x & 63;
    int cntM = counts[b*16 + 8];
    int nw = gridDim.x*4;
    float cb0 = conv_b[lane], cb1 = conv_b[lane + 64];
    float rb0 = fmaxf(cb0, 0.0f), rb1 = fmaxf(cb1, 0.0f);

    for (int i = wave; i < cntM; i += nw) {
        int pc = mList[(size_t)b*MAXACT + i].x;
        int x0 = pc >> 12, y0 = (pc >> 6) & 63, z0 = pc & 63;
        // fc weights early (independent of acc chain)
        int flat = x0*1600 + (RR-1 - y0)*RR + (RR-1 - z0);
        float w0, w1;
        if (useT) {
            w0 = fcT[(size_t)flat*C + lane];
            w1 = fcT[(size_t)flat*C + lane + 64];
        } else {
            w0 = fc_w[(size_t)lane*VOX + flat];
            w1 = fc_w[(size_t)(lane + 64)*VOX + flat];
        }
        int sl = -1;
        if (lane < 27) {
            int dp = lane/9, dq = (lane/3)%3, dr = lane%3;
            int nx = x0 + dp - 1, ny = y0 + 1 - dq, nz = z0 + 1 - dr;
            if (nx >= 0 && nx < RR && ny >= 0 && ny < RR && nz >= 0 && nz < RR)
                sl = slotGrid[(size_t)b*VOX + (nx*RR + ny)*RR + nz];
        }
        unsigned long long mask = __ballot(sl >= 0);
        float acc0 = 0.0f, acc1 = 0.0f;
        while (mask) {
            int eA = __builtin_ctzll(mask); mask &= mask - 1;
            int eB = eA;
            bool two = (mask != 0ull);
            if (two) { eB = __builtin_ctzll(mask); mask &= mask - 1; }
            int slA = __shfl(sl, eA);
            int slB = __shfl(sl, eB);
            float v0 = 0.0f, v1 = 0.0f;
            if (lane < F) {
                v0 = feats[((size_t)b*MAXOCC + slA)*F + lane];
                v1 = two ? feats[((size_t)b*MAXOCC + slB)*F + lane] : 0.0f;
            }
            const float* wpA = Wt + (size_t)eA*F*C;
            const float* wpB = Wt + (size_t)eB*F*C;
            #pragma unroll 9
            for (int f = 0; f < F; f++) {
                float fA = __shfl(v0, f);
                float fB = __shfl(v1, f);
                acc0 = fmaf(fA, wpA[f*C + lane],      acc0);
                acc1 = fmaf(fA, wpA[f*C + lane + 64], acc1);
                acc0 = fmaf(fB, wpB[f*C + lane],      acc0);
                acc1 = fmaf(fB, wpB[f*C + lane + 64], acc1);
            }
        }
        float o0 = fmaxf(acc0 + cb0, 0.0f) - rb0;
        float o1 = fmaxf(acc1 + cb1, 0.0f) - rb1;
        float s = fmaf(o0, w0, o1*w1);
        #pragma unroll
        for (int off = 32; off; off >>= 1) s += __shfl_xor(s, off);
        if (lane == 0) bsum[(size_t)b*BSR + 1024 + i] = s;
    }
}

// ---------------- K9: deterministic per-batch reduce + background + sigmoid ----------------
__global__ __launch_bounds__(1024)
void k_reduce(const float* __restrict__ bsum, const float* __restrict__ bgBlock,
              const float* __restrict__ fc_b, const int* __restrict__ counts,
              float* __restrict__ out) {
    int b = blockIdx.x;
    int t = threadIdx.x;  // 1024
    float s = 0.0f;
    for (int i = t; i < 27*NCHUNK; i += 1024) s += bsum[(size_t)b*BSR + i];
    int cntM = counts[b*16 + 8];
    for (int i = t; i < cntM; i += 1024) s += bsum[(size_t)b*BSR + 1024 + i];
    for (int i = t; i < NBG; i += 1024) s += bgBlock[i];
    #pragma unroll
    for (int off = 32; off; off >>= 1) s += __shfl_xor(s, off);
    __shared__ float red[16];
    if ((t & 63) == 0) red[t >> 6] = s;
    __syncthreads();
    if (t == 0) {
        float tot = fc_b[0];
        #pragma unroll
        for (int i = 0; i < 16; i++) tot += red[i];
        out[b] = 1.0f / (1.0f + expf(-tot));
    }
}

extern "C" void kernel_launch(void* const* d_in, const int* in_sizes, int n_in,
                              void* d_out, int out_size, void* d_ws, size_t ws_size,
                              hipStream_t stream) {
    const float* pos1   = (const float*)d_in[0];
    const float* pos2   = (const float*)d_in[1];
    const float* h1     = (const float*)d_in[2];
    const float* h2     = (const float*)d_in[3];
    const float* valid1 = (const float*)d_in[4];
    const float* valid2 = (const float*)d_in[5];
    const float* conv_w = (const float*)d_in[6];
    const float* conv_b = (const float*)d_in[7];
    const float* fc_w   = (const float*)d_in[8];
    const float* fc_b   = (const float*)d_in[9];
    float* out = (float*)d_out;

    char* ws = (char*)d_ws;
    float*    sub      = (float*)   (ws + OFF_SUB);
    int*      winner   = (int*)     (ws + OFF_WIN);
    int*      slotGrid = (int*)     (ws + OFF_SLOT);
    unsigned* actFirst = (unsigned*)(ws + OFF_AFST);
    int*      actCnt   = (int*)     (ws + OFF_ACNTG);
    int*      counts   = (int*)     (ws + OFF_CNTS);
    int*      bCnt     = (int*)     (ws + OFF_BCNT);
    int*      occCoords= (int*)     (ws + OFF_OCC);
    float*    feats    = (float*)   (ws + OFF_FEAT);
    float*    Wt       = (float*)   (ws + OFF_WT);
    float*    bgBlock  = (float*)   (ws + OFF_BG);
    int2*     sBuck    = (int2*)    (ws + OFF_SBUK);
    int2*     mList    = (int2*)    (ws + OFF_MLST);
    float*    bsum     = (float*)   (ws + OFF_BSUM);
    float*    fcT      = (float*)   (ws + OFF_FCT);

    const int useT = (ws_size >= OFF_END) ? 1 : 0;

    // per-call re-init (harness does not re-poison between replays) — 2 fused memsets
    hipMemsetAsync(ws + OFF_WIN,   0xFF, FF_END - OFF_WIN,   stream);
    hipMemsetAsync(ws + OFF_ACNTG, 0x00, Z_END - OFF_ACNTG,  stream);

    k_init<<<B + WT_BLKS, 64, 0, stream>>>(pos1, valid1, sub, conv_w, Wt);
    k_scatter<<<(B*NP + 255)/256, 256, 0, stream>>>(pos1, valid1, pos2, valid2, sub, winner);
    k_claim<<<(B*NP + 255)/256, 256, 0, stream>>>(pos1, valid1, pos2, valid2, h1, h2,
                                                  sub, winner, slotGrid, counts, occCoords, feats);
    k_dilate<<<(B*MAXOCC*27 + 255)/256, 256, 0, stream>>>(counts, occCoords, actCnt, actFirst);
    if (useT) {
        k_fct_compact<<<dim3(CPB + VOX/64, B), 256, 0, stream>>>(
            fc_w, conv_b, fcT, bgBlock,
            counts, occCoords, actCnt, actFirst, counts, bCnt, sBuck, mList);
    } else {
        k_compact<<<(B*27*PPS)/256, 256, 0, stream>>>(counts, occCoords, actCnt, actFirst,
                                                      counts, bCnt, sBuck, mList);
        hipMemsetAsync(bgBlock, 0x00, (size_t)NBG*4, stream);
        k_bg_fb<<<C, 256, 0, stream>>>(fc_w, conv_b, bgBlock);
    }
    k_convS<<<dim3(27*NCHUNK, B), 128, 0, stream>>>(feats, bCnt, sBuck, Wt, conv_b,
                                                    fcT, fc_w, useT, bsum);
    k_convM<<<dim3(512, B), 256, 0, stream>>>(slotGrid, feats, counts, mList,
                                              Wt, conv_b, fcT, fc_w, useT, bsum);
    k_reduce<<<B, 1024, 0, stream>>>(bsum, bgBlock, fc_b, counts, out);
}

// Round 14
// 121.816 us; speedup vs baseline: 1.2153x; 1.0034x over previous
//
#include <hip/hip_runtime.h>
#include <float.h>
#include <math.h>

// Problem constants (fixed shapes from setup_inputs)
constexpr int B = 8, N1 = 400, N2 = 64, NP = N1 + N2, F = 54, C = 128;
constexpr int RR = 40;        // lattice size after slicing
constexpr int RG = 41;        // scatter grid (includes dump cell at 40,40,40)
constexpr int VOX = RR*RR*RR; // 64000
constexpr int MAXOCC = NP;            // max occupied voxels per batch
constexpr int MAXACT = NP * 27;       // max multi voxels per batch
constexpr int NBG = (VOX/64) * (C/16);     // 8000 background partials
constexpr int PCHUNK = 16;            // pairs per k_convS block
constexpr int NCHUNK = 32;            // chunks per (b,sten) bucket
constexpr int BSR = 16384;            // bsum region per batch (singles [0,864), multi 1024+)
constexpr int PPS = 512;              // padded s-range per (b,k) in k_compact
constexpr int CPB = 54;               // compact blocks per batch (27*512/256)

constexpr size_t align256(size_t x) { return (x + 255) & ~(size_t)255; }

// Workspace layout — 0xFF-init grids contiguous, then 0x00-init grids contiguous
constexpr size_t OFF_SUB   = 0;                                   // B*3 f32
constexpr size_t OFF_WIN   = align256(OFF_SUB  + (size_t)B*3*4);  // B*41^3 i32   (0xFF)
constexpr size_t SZ_WIN    = (size_t)B*RG*RG*RG*4;
constexpr size_t OFF_SLOT  = align256(OFF_WIN  + SZ_WIN);         // B*40^3 i32   (0xFF)
constexpr size_t SZ_SLOT   = (size_t)B*VOX*4;
constexpr size_t OFF_AFST  = align256(OFF_SLOT + SZ_SLOT);        // B*40^3 u32   (0xFF)
constexpr size_t FF_END    = OFF_AFST + SZ_SLOT;
constexpr size_t OFF_ACNTG = align256(FF_END);                    // B*40^3 i32   (0x00)
constexpr size_t OFF_CNTS  = align256(OFF_ACNTG+ SZ_SLOT);        // B*16 i32     (0x00)
constexpr size_t OFF_BCNT  = align256(OFF_CNTS + (size_t)B*16*4); // 27*B*16 i32  (0x00)
constexpr size_t SZ_BCNT   = (size_t)B*27*16*4;
constexpr size_t Z_END     = OFF_BCNT + SZ_BCNT;
constexpr size_t OFF_OCC   = align256(Z_END);                     // B*MAXOCC i32
constexpr size_t OFF_FEAT  = align256(OFF_OCC  + (size_t)B*MAXOCC*4); // B*MAXOCC*F f32
constexpr size_t OFF_WT    = align256(OFF_FEAT + (size_t)B*MAXOCC*F*4); // 27*F*C f32
constexpr size_t OFF_BG    = align256(OFF_WT   + (size_t)27*F*C*4);     // NBG f32
constexpr size_t OFF_SBUK  = align256(OFF_BG   + (size_t)NBG*4);        // B*27*MAXOCC int2
constexpr size_t OFF_MLST  = align256(OFF_SBUK + (size_t)B*27*MAXOCC*8);// B*MAXACT int2
constexpr size_t OFF_BSUM  = align256(OFF_MLST + (size_t)B*MAXACT*8);   // B*BSR f32
constexpr size_t OFF_FCT   = align256(OFF_BSUM + (size_t)B*BSR*4);      // VOX*C f32
constexpr size_t OFF_END   = OFF_FCT + (size_t)VOX*C*4;

constexpr int WT_BLKS = (27*F*C + 63)/64;

// ---------------- K1: bbox (blocks 0..B-1) + conv_w transpose (rest) ----------------
__global__ __launch_bounds__(64)
void k_init(const float* __restrict__ pos1, const float* __restrict__ valid1,
            float* __restrict__ sub, const float* __restrict__ conv_w,
            float* __restrict__ Wt) {
    if (blockIdx.x < B) {
        int b = blockIdx.x;
        int t = threadIdx.x;
        float bmax[3] = {-FLT_MAX, -FLT_MAX, -FLT_MAX};
        float bmin[3] = { FLT_MAX,  FLT_MAX,  FLT_MAX};
        for (int n = t; n < N1; n += 64) {
            float v = valid1[b*N1 + n];
            const float* pp = pos1 + ((size_t)b*N1 + n)*3;
            float p0 = pp[0]*v, p1 = pp[1]*v, p2 = pp[2]*v;
            float s = p0 + p1 + p2;
            bool nz = (s == 0.0f);
            float amax = nz ? -10000000000.0f : 0.0f;
            float amin = nz ?  10000000000.0f : 0.0f;
            bmax[0] = fmaxf(bmax[0], p0 + amax);
            bmax[1] = fmaxf(bmax[1], p1 + amax);
            bmax[2] = fmaxf(bmax[2], p2 + amax);
            bmin[0] = fminf(bmin[0], p0 + amin);
            bmin[1] = fminf(bmin[1], p1 + amin);
            bmin[2] = fminf(bmin[2], p2 + amin);
        }
        #pragma unroll
        for (int off = 32; off; off >>= 1) {
            #pragma unroll
            for (int d = 0; d < 3; d++) {
                bmax[d] = fmaxf(bmax[d], __shfl_xor(bmax[d], off));
                bmin[d] = fminf(bmin[d], __shfl_xor(bmin[d], off));
            }
        }
        if (t == 0) {
            #pragma unroll
            for (int d = 0; d < 3; d++)
                sub[b*3 + d] = bmin[d] + (bmax[d] - bmin[d]) / 2.0f;
        }
    } else {
        int g = (blockIdx.x - B)*64 + threadIdx.x;
        if (g < 27*F*C) {
            int o = g & (C-1);
            int rest = g >> 7;       // C==128
            int f = rest % F, s = rest / F;
            Wt[g] = conv_w[((size_t)o*F + f)*27 + s];
        }
    }
}

// helper: compute voxel index for global point n (n<N1 -> pos1 else pos2)
__device__ inline void point_idx(const float* pos1, const float* valid1,
                                 const float* pos2, const float* valid2,
                                 const float* sub, int b, int n,
                                 int& ix, int& iy, int& iz, bool& inb, float& vout) {
    float px, py, pz, v;
    if (n < N1) {
        v = valid1[b*N1 + n];
        const float* p = pos1 + ((size_t)b*N1 + n)*3;
        px = p[0]*v; py = p[1]*v; pz = p[2]*v;
    } else {
        int m = n - N1;
        v = valid2[b*N2 + m];
        const float* p = pos2 + ((size_t)b*N2 + m)*3;
        px = p[0]*v; py = p[1]*v; pz = p[2]*v;
    }
    const float* sb = sub + b*3;
    ix = (int)floorf((px - sb[0] + 10.0f) / 0.5f);
    iy = (int)floorf((py - sb[1] + 10.0f) / 0.5f);
    iz = (int)floorf((pz - sb[2] + 10.0f) / 0.5f);
    inb = (ix >= 0 && ix <= RR-1 && iy >= 0 && iy <= RR-1 && iz >= 0 && iz <= RR-1);
    vout = v;
}

// ---------------- K2: winner scatter (last-write-wins via atomicMax) ----------------
__global__ void k_scatter(const float* __restrict__ pos1, const float* __restrict__ valid1,
                          const float* __restrict__ pos2, const float* __restrict__ valid2,
                          const float* __restrict__ sub, int* __restrict__ winner) {
    int g = blockIdx.x*blockDim.x + threadIdx.x;
    if (g >= B*NP) return;
    int b = g / NP, n = g % NP;
    int ix, iy, iz; bool inb; float v;
    point_idx(pos1, valid1, pos2, valid2, sub, b, n, ix, iy, iz, inb, v);
    int x = inb ? ix : RR, y = inb ? iy : RR, z = inb ? iz : RR;
    int cell = (x*RG + y)*RG + z;
    atomicMax(&winner[(size_t)b*RG*RG*RG + cell], n);
}

// ---------------- K3: claim winners, compact occupied list + features ----------------
__global__ void k_claim(const float* __restrict__ pos1, const float* __restrict__ valid1,
                        const float* __restrict__ pos2, const float* __restrict__ valid2,
                        const float* __restrict__ h1, const float* __restrict__ h2,
                        const float* __restrict__ sub, const int* __restrict__ winner,
                        int* __restrict__ slotGrid, int* __restrict__ counts,
                        int* __restrict__ occCoords, float* __restrict__ feats) {
    int g = blockIdx.x*blockDim.x + threadIdx.x;
    if (g >= B*NP) return;
    int b = g / NP, n = g % NP;
    int ix, iy, iz; bool inb; float v;
    point_idx(pos1, valid1, pos2, valid2, sub, b, n, ix, iy, iz, inb, v);
    if (!inb) return;  // dump cell (40,40,40) is sliced off
    int cell = (ix*RG + iy)*RG + iz;
    if (winner[(size_t)b*RG*RG*RG + cell] != n) return;
    int slot = atomicAdd(&counts[b*16], 1);
    slotGrid[(size_t)b*VOX + (ix*RR + iy)*RR + iz] = slot;
    occCoords[b*MAXOCC + slot] = (ix << 12) | (iy << 6) | iz;
    const float* h = (n < N1) ? (h1 + ((size_t)b*N1 + n)*F)
                              : (h2 + ((size_t)b*N2 + (n - N1))*F);
    float* fo = feats + ((size_t)b*MAXOCC + slot)*F;
    for (int f = 0; f < F; f++) fo[f] = h[f] * v;
}

// ---------------- K4: dilate -> contributor count + deterministic owner (atomicMin) ----------------
__global__ void k_dilate(const int* __restrict__ counts, const int* __restrict__ occCoords,
                         int* __restrict__ actCnt, unsigned* __restrict__ actFirst) {
    int g = blockIdx.x*blockDim.x + threadIdx.x;
    if (g >= B*MAXOCC*27) return;
    int b = g / (MAXOCC*27);
    int rem = g % (MAXOCC*27);
    int sl = rem / 27, k = rem % 27;
    if (sl >= counts[b*16]) return;
    int pc = occCoords[b*MAXOCC + sl];
    int x = pc >> 12, y = (pc >> 6) & 63, z = pc & 63;
    int nx = x + k/9 - 1, ny = y + (k/3)%3 - 1, nz = z + k%3 - 1;
    if (nx < 0 || nx >= RR || ny < 0 || ny >= RR || nz < 0 || nz >= RR) return;
    size_t lin = (size_t)b*VOX + (nx*RR + ny)*RR + nz;
    atomicAdd(&actCnt[lin], 1);
    int sten = (2 - k/9)*9 + ((k/3)%3)*3 + (k%3);
    atomicMin(&actFirst[lin], ((unsigned)sl << 5) | (unsigned)sten);
}

// ---------------- shared compact body ----------------
__device__ inline void compact_body(int g,
               const int* __restrict__ counts, const int* __restrict__ occCoords,
               const int* __restrict__ actCnt, const unsigned* __restrict__ actFirst,
               int* __restrict__ countsW, int* __restrict__ bCnt,
               int2* __restrict__ sBuck, int2* __restrict__ mList, int lane) {
    int bucket = g / PPS;          // b*27 + k
    int s = g % PPS;
    int b = bucket / 27, k = bucket % 27;
    if (b >= B) return;
    int sten = (2 - k/9)*9 + ((k/3)%3)*3 + (k%3);  // wave-uniform (bijection of k)
    bool ownS = false, ownM = false; int pcOut = 0;
    if (s < counts[b*16]) {
        int pc = occCoords[b*MAXOCC + s];
        int x = pc >> 12, y = (pc >> 6) & 63, z = pc & 63;
        int x0 = x + k/9 - 1, y0 = y + (k/3)%3 - 1, z0 = z + k%3 - 1;
        if (x0 >= 0 && x0 < RR && y0 >= 0 && y0 < RR && z0 >= 0 && z0 < RR) {
            size_t lin = (size_t)b*VOX + (x0*RR + y0)*RR + z0;
            unsigned myid = ((unsigned)s << 5) | (unsigned)sten;
            if (actFirst[lin] == myid) {
                pcOut = (x0 << 12) | (y0 << 6) | z0;
                if (actCnt[lin] == 1) ownS = true; else ownM = true;
            }
        }
    }
    unsigned long long mS = __ballot(ownS);
    if (mS != 0ull) {
        int lead = __builtin_ctzll(mS);
        int base = 0;
        if (lane == lead) base = atomicAdd(&bCnt[(b*27 + sten)*16], __popcll(mS));
        base = __shfl(base, lead);
        if (ownS) {
            int rank = __popcll(mS & ((1ull << lane) - 1ull));
            sBuck[((size_t)(b*27 + sten))*MAXOCC + base + rank] = make_int2(pcOut, s);
        }
    }
    unsigned long long mM = __ballot(ownM);
    if (mM != 0ull) {
        int lead = __builtin_ctzll(mM);
        int base = 0;
        if (lane == lead) base = atomicAdd(&countsW[b*16 + 8], __popcll(mM));
        base = __shfl(base, lead);
        if (ownM) {
            int rank = __popcll(mM & ((1ull << lane) - 1ull));
            mList[(size_t)b*MAXACT + base + rank] = make_int2(pcOut, 0);
        }
    }
}

// ---------------- K5: standalone compact (fallback path) ----------------
__global__ __launch_bounds__(256)
void k_compact(const int* __restrict__ counts, const int* __restrict__ occCoords,
               const int* __restrict__ actCnt, const unsigned* __restrict__ actFirst,
               int* __restrict__ countsW, int* __restrict__ bCnt,
               int2* __restrict__ sBuck, int2* __restrict__ mList) {
    int g = blockIdx.x*256 + threadIdx.x;
    compact_body(g, counts, occCoords, actCnt, actFirst, countsW, bCnt, sBuck, mList,
                 threadIdx.x & 63);
}

// ---------------- K6: fused fc_w transpose + background partials + compact ----------------
__global__ __launch_bounds__(256)
void k_fct_compact(const float* __restrict__ fc_w, const float* __restrict__ conv_b,
                   float* __restrict__ fcT, float* __restrict__ bgBlock,
                   const int* __restrict__ counts, const int* __restrict__ occCoords,
                   const int* __restrict__ actCnt, const unsigned* __restrict__ actFirst,
                   int* __restrict__ countsW, int* __restrict__ bCnt,
                   int2* __restrict__ sBuck, int2* __restrict__ mList) {
    if (blockIdx.x < CPB) {
        int g = ((int)blockIdx.y*CPB + blockIdx.x)*256 + threadIdx.x;
        compact_body(g, counts, occCoords, actCnt, actFirst, countsW, bCnt, sBuck, mList,
                     threadIdx.x & 63);
        return;
    }
    __shared__ float tile[16][65];
    __shared__ float sred[16][17];
    __shared__ float sredw[16];
    int v0 = (blockIdx.x - CPB) * 64;  // 1000 v-blocks
    int o0 = blockIdx.y * 16;          // 8 o-blocks (B == C/16)
    int t = threadIdx.x;               // 256
    int tv = t & 63, to = t >> 6;
    #pragma unroll
    for (int oo = 0; oo < 16; oo += 4)
        tile[to + oo][tv] = fc_w[(size_t)(o0 + to + oo)*VOX + v0 + tv];
    __syncthreads();
    int to2 = t & 15, tv2 = t >> 4;
    float s = 0.0f;
    #pragma unroll
    for (int vv = 0; vv < 64; vv += 16) {
        float val = tile[to2][tv2 + vv];
        fcT[(size_t)(v0 + tv2 + vv)*C + o0 + to2] = val;
        s += val;
    }
    sred[to2][tv2] = s;
    __syncthreads();
    if (t < 16) {
        float tot = 0.0f;
        #pragma unroll
        for (int i = 0; i < 16; i++) tot += sred[t][i];
        sredw[t] = fmaxf(conv_b[o0 + t], 0.0f) * tot;
    }
    __syncthreads();
    if (t == 0) {
        float tot = 0.0f;
        #pragma unroll
        for (int i = 0; i < 16; i++) tot += sredw[i];
        bgBlock[blockIdx.y*1000 + (blockIdx.x - CPB)] = tot;
    }
}

// ---------------- K6b: fallback background when fcT doesn't fit ----------------
__global__ __launch_bounds__(256)
void k_bg_fb(const float* __restrict__ fc_w, const float* __restrict__ conv_b,
             float* __restrict__ bgBlock) {
    int o = blockIdx.x;  // 128
    int t = threadIdx.x; // 256
    float s = 0.0f;
    for (int v = t; v < VOX; v += 256) s += fc_w[(size_t)o*VOX + v];
    #pragma unroll
    for (int off = 32; off; off >>= 1) s += __shfl_xor(s, off);
    __shared__ float red4[4];
    if ((t & 63) == 0) red4[t >> 6] = s;
    __syncthreads();
    if (t == 0) bgBlock[o] = fmaxf(conv_b[o], 0.0f) * (red4[0] + red4[1] + red4[2] + red4[3]);
}

// ---------------- K7: singles conv (r7 structure + fcT prefetch) ----------------
// block = (b, sten, chunk); thread t = channel; Wt slice read once per f for 16 pairs
__global__ __launch_bounds__(128)
void k_convS(const float* __restrict__ feats, const int* __restrict__ bCnt,
             const int2* __restrict__ sBuck, const float* __restrict__ Wt,
             const float* __restrict__ conv_b, const float* __restrict__ fcT,
             const float* __restrict__ fc_w, int useT, float* __restrict__ bsum) {
    int b = blockIdx.y;
    int sten = blockIdx.x >> 5;
    int chunk = blockIdx.x & 31;
    int t = threadIdx.x;  // 128 = channels
    int idxOut = sten*NCHUNK + chunk;
    int cnt = bCnt[(b*27 + sten)*16];
    int base = chunk*PCHUNK;
    if (base >= cnt) { if (t == 0) bsum[(size_t)b*BSR + idxOut] = 0.0f; return; }
    int rem = min(PCHUNK, cnt - base);

    __shared__ float fLDS[54][20];   // stride 20 floats (80B, 16B-aligned rows)
    __shared__ int   flatS[16];
    __shared__ int   slotS[16];
    __shared__ float red[2];

    if (t < 16) {
        if (t < rem) {
            int2 e = sBuck[((size_t)(b*27 + sten))*MAXOCC + base + t];
            int pc = e.x;
            int x0 = pc >> 12, y0 = (pc >> 6) & 63, z0 = pc & 63;
            flatS[t] = x0*1600 + (RR-1 - y0)*RR + (RR-1 - z0);
            slotS[t] = e.y;
        } else { flatS[t] = 0; slotS[t] = -1; }
    }
    __syncthreads();

    // T14-style prefetch: issue the 16 scattered fc-weight loads NOW so their
    // ~900cy HBM latency hides under feature staging + the 54-iter f-loop.
    float wf[16];
    #pragma unroll
    for (int p = 0; p < 16; p++)
        wf[p] = useT ? fcT[(size_t)flatS[p]*C + t]
                     : fc_w[(size_t)t*VOX + flatS[p]];

    for (int idx = t; idx < PCHUNK*F; idx += 128) {
        int p = idx / F, f = idx - p*F;
        int sl = slotS[p];
        fLDS[f][p] = (sl >= 0) ? feats[((size_t)b*MAXOCC + sl)*F + f] : 0.0f;
    }
    __syncthreads();

    const float* wv = Wt + (size_t)sten*F*C + t;
    float acc[16];
    #pragma unroll
    for (int p = 0; p < 16; p++) acc[p] = 0.0f;
    #pragma unroll 3
    for (int f = 0; f < F; f++) {
        float w = wv[(size_t)f*C];
        float4 a = *(const float4*)&fLDS[f][0];
        float4 q = *(const float4*)&fLDS[f][4];
        float4 c = *(const float4*)&fLDS[f][8];
        float4 d = *(const float4*)&fLDS[f][12];
        acc[0]  = fmaf(a.x, w, acc[0]);  acc[1]  = fmaf(a.y, w, acc[1]);
        acc[2]  = fmaf(a.z, w, acc[2]);  acc[3]  = fmaf(a.w, w, acc[3]);
        acc[4]  = fmaf(q.x, w, acc[4]);  acc[5]  = fmaf(q.y, w, acc[5]);
        acc[6]  = fmaf(q.z, w, acc[6]);  acc[7]  = fmaf(q.w, w, acc[7]);
        acc[8]  = fmaf(c.x, w, acc[8]);  acc[9]  = fmaf(c.y, w, acc[9]);
        acc[10] = fmaf(c.z, w, acc[10]); acc[11] = fmaf(c.w, w, acc[11]);
        acc[12] = fmaf(d.x, w, acc[12]); acc[13] = fmaf(d.y, w, acc[13]);
        acc[14] = fmaf(d.z, w, acc[14]); acc[15] = fmaf(d.w, w, acc[15]);
    }
    float cb = conv_b[t];
    float rb = fmaxf(cb, 0.0f);
    float ssum = 0.0f;
    #pragma unroll
    for (int p = 0; p < 16; p++) {
        if (p < rem) {
            float outv = fmaxf(acc[p] + cb, 0.0f) - rb;
            ssum = fmaf(outv, wf[p], ssum);
        }
    }
    #pragma unroll
    for (int off = 32; off; off >>= 1) ssum += __shfl_xor(ssum, off);
    if ((t & 63) == 0) red[t >> 6] = ssum;
    __syncthreads();
    if (t == 0) bsum[(size_t)b*BSR + idxOut] = red[0] + red[1];
}

// ---------------- K8: multi conv — 1 wave/voxel, paired shuffle-broadcast (r7) ----------------
__global__ __launch_bounds__(256)
void k_convM(const int* __restrict__ slotGrid, const float* __restrict__ feats,
             const int* __restrict__ counts, const int2* __restrict__ mList,
             const float* __restrict__ Wt, const float* __restrict__ conv_b,
             const float* __restrict__ fcT, const float* __restrict__ fc_w, int useT,
             float* __restrict__ bsum) {
    int b = blockIdx.y;
    int wave = blockIdx.x*4 + (threadIdx.x >> 6);
    int lane = threadIdx.x & 63;
    int cntM = counts[b*16 + 8];
    int nw = gridDim.x*4;
    float cb0 = conv_b[lane], cb1 = conv_b[lane + 64];
    float rb0 = fmaxf(cb0, 0.0f), rb1 = fmaxf(cb1, 0.0f);

    for (int i = wave; i < cntM; i += nw) {
        int pc = mList[(size_t)b*MAXACT + i].x;
        int x0 = pc >> 12, y0 = (pc >> 6) & 63, z0 = pc & 63;
        // fc weights early (independent of acc chain)
        int flat = x0*1600 + (RR-1 - y0)*RR + (RR-1 - z0);
        float w0, w1;
        if (useT) {
            w0 = fcT[(size_t)flat*C + lane];
            w1 = fcT[(size_t)flat*C + lane + 64];
        } else {
            w0 = fc_w[(size_t)lane*VOX + flat];
            w1 = fc_w[(size_t)(lane + 64)*VOX + flat];
        }
        int sl = -1;
        if (lane < 27) {
            int dp = lane/9, dq = (lane/3)%3, dr = lane%3;
            int nx = x0 + dp - 1, ny = y0 + 1 - dq, nz = z0 + 1 - dr;
            if (nx >= 0 && nx < RR && ny >= 0 && ny < RR && nz >= 0 && nz < RR)
                sl = slotGrid[(size_t)b*VOX + (nx*RR + ny)*RR + nz];
        }
        unsigned long long mask = __ballot(sl >= 0);
        float acc0 = 0.0f, acc1 = 0.0f;
        while (mask) {
            int eA = __builtin_ctzll(mask); mask &= mask - 1;
            int eB = eA;
            bool two = (mask != 0ull);
            if (two) { eB = __builtin_ctzll(mask); mask &= mask - 1; }
            int slA = __shfl(sl, eA);
            int slB = __shfl(sl, eB);
            float v0 = 0.0f, v1 = 0.0f;
            if (lane < F) {
                v0 = feats[((size_t)b*MAXOCC + slA)*F + lane];
                v1 = two ? feats[((size_t)b*MAXOCC + slB)*F + lane] : 0.0f;
            }
            const float* wpA = Wt + (size_t)eA*F*C;
            const float* wpB = Wt + (size_t)eB*F*C;
            #pragma unroll 9
            for (int f = 0; f < F; f++) {
                float fA = __shfl(v0, f);
                float fB = __shfl(v1, f);
                acc0 = fmaf(fA, wpA[f*C + lane],      acc0);
                acc1 = fmaf(fA, wpA[f*C + lane + 64], acc1);
                acc0 = fmaf(fB, wpB[f*C + lane],      acc0);
                acc1 = fmaf(fB, wpB[f*C + lane + 64], acc1);
            }
        }
        float o0 = fmaxf(acc0 + cb0, 0.0f) - rb0;
        float o1 = fmaxf(acc1 + cb1, 0.0f) - rb1;
        float s = fmaf(o0, w0, o1*w1);
        #pragma unroll
        for (int off = 32; off; off >>= 1) s += __shfl_xor(s, off);
        if (lane == 0) bsum[(size_t)b*BSR + 1024 + i] = s;
    }
}

// ---------------- K9: deterministic per-batch reduce + background + sigmoid ----------------
__global__ __launch_bounds__(1024)
void k_reduce(const float* __restrict__ bsum, const float* __restrict__ bgBlock,
              const float* __restrict__ fc_b, const int* __restrict__ counts,
              float* __restrict__ out) {
    int b = blockIdx.x;
    int t = threadIdx.x;  // 1024
    float s = 0.0f;
    for (int i = t; i < 27*NCHUNK; i += 1024) s += bsum[(size_t)b*BSR + i];
    int cntM = counts[b*16 + 8];
    for (int i = t; i < cntM; i += 1024) s += bsum[(size_t)b*BSR + 1024 + i];
    for (int i = t; i < NBG; i += 1024) s += bgBlock[i];
    #pragma unroll
    for (int off = 32; off; off >>= 1) s += __shfl_xor(s, off);
    __shared__ float red[16];
    if ((t & 63) == 0) red[t >> 6] = s;
    __syncthreads();
    if (t == 0) {
        float tot = fc_b[0];
        #pragma unroll
        for (int i = 0; i < 16; i++) tot += red[i];
        out[b] = 1.0f / (1.0f + expf(-tot));
    }
}

extern "C" void kernel_launch(void* const* d_in, const int* in_sizes, int n_in,
                              void* d_out, int out_size, void* d_ws, size_t ws_size,
                              hipStream_t stream) {
    const float* pos1   = (const float*)d_in[0];
    const float* pos2   = (const float*)d_in[1];
    const float* h1     = (const float*)d_in[2];
    const float* h2     = (const float*)d_in[3];
    const float* valid1 = (const float*)d_in[4];
    const float* valid2 = (const float*)d_in[5];
    const float* conv_w = (const float*)d_in[6];
    const float* conv_b = (const float*)d_in[7];
    const float* fc_w   = (const float*)d_in[8];
    const float* fc_b   = (const float*)d_in[9];
    float* out = (float*)d_out;

    char* ws = (char*)d_ws;
    float*    sub      = (float*)   (ws + OFF_SUB);
    int*      winner   = (int*)     (ws + OFF_WIN);
    int*      slotGrid = (int*)     (ws + OFF_SLOT);
    unsigned* actFirst = (unsigned*)(ws + OFF_AFST);
    int*      actCnt   = (int*)     (ws + OFF_ACNTG);
    int*      counts   = (int*)     (ws + OFF_CNTS);
    int*      bCnt     = (int*)     (ws + OFF_BCNT);
    int*      occCoords= (int*)     (ws + OFF_OCC);
    float*    feats    = (float*)   (ws + OFF_FEAT);
    float*    Wt       = (float*)   (ws + OFF_WT);
    float*    bgBlock  = (float*)   (ws + OFF_BG);
    int2*     sBuck    = (int2*)    (ws + OFF_SBUK);
    int2*     mList    = (int2*)    (ws + OFF_MLST);
    float*    bsum     = (float*)   (ws + OFF_BSUM);
    float*    fcT      = (float*)   (ws + OFF_FCT);

    const int useT = (ws_size >= OFF_END) ? 1 : 0;

    // per-call re-init (harness does not re-poison between replays) — 2 fused memsets
    hipMemsetAsync(ws + OFF_WIN,   0xFF, FF_END - OFF_WIN,   stream);
    hipMemsetAsync(ws + OFF_ACNTG, 0x00, Z_END - OFF_ACNTG,  stream);

    k_init<<<B + WT_BLKS, 64, 0, stream>>>(pos1, valid1, sub, conv_w, Wt);
    k_scatter<<<(B*NP + 255)/256, 256, 0, stream>>>(pos1, valid1, pos2, valid2, sub, winner);
    k_claim<<<(B*NP + 255)/256, 256, 0, stream>>>(pos1, valid1, pos2, valid2, h1, h2,
                                                  sub, winner, slotGrid, counts, occCoords, feats);
    k_dilate<<<(B*MAXOCC*27 + 255)/256, 256, 0, stream>>>(counts, occCoords, actCnt, actFirst);
    if (useT) {
        k_fct_compact<<<dim3(CPB + VOX/64, B), 256, 0, stream>>>(
            fc_w, conv_b, fcT, bgBlock,
            counts, occCoords, actCnt, actFirst, counts, bCnt, sBuck, mList);
    } else {
        k_compact<<<(B*27*PPS)/256, 256, 0, stream>>>(counts, occCoords, actCnt, actFirst,
                                                      counts, bCnt, sBuck, mList);
        hipMemsetAsync(bgBlock, 0x00, (size_t)NBG*4, stream);
        k_bg_fb<<<C, 256, 0, stream>>>(fc_w, conv_b, bgBlock);
    }
    k_convS<<<dim3(27*NCHUNK, B), 128, 0, stream>>>(feats, bCnt, sBuck, Wt, conv_b,
                                                    fcT, fc_w, useT, bsum);
    k_convM<<<dim3(512, B), 256, 0, stream>>>(slotGrid, feats, counts, mList,
                                              Wt, conv_b, fcT, fc_w, useT, bsum);
    k_reduce<<<B, 1024, 0, stream>>>(bsum, bgBlock, fc_b, counts, out);
}

// Round 15
// 116.099 us; speedup vs baseline: 1.2751x; 1.0492x over previous
//
#include <hip/hip_runtime.h>
#include <float.h>
#include <math.h>

// Problem constants (fixed shapes from setup_inputs)
constexpr int B = 8, N1 = 400, N2 = 64, NP = N1 + N2, F = 54, C = 128;
constexpr int RR = 40;        // lattice size after slicing
constexpr int RG = 41;        // scatter grid (includes dump cell at 40,40,40)
constexpr int VOX = RR*RR*RR; // 64000
constexpr int MAXOCC = NP;            // max occupied voxels per batch
constexpr int MAXACT = NP * 27;       // max multi voxels per batch
constexpr int NBG = (VOX/64) * (C/16);     // 8000 background partials
constexpr int PCHUNK = 16;            // pairs per k_convS block
constexpr int NCHUNK = 32;            // chunks per (b,sten) bucket
constexpr int BSR = 16384;            // bsum region per batch (singles [0,864), multi 1024+)
constexpr int PPS = 512;              // padded s-range per (b,k) in k_compact
constexpr int CPB = 54;               // compact blocks per batch (27*512/256)

constexpr size_t align256(size_t x) { return (x + 255) & ~(size_t)255; }

// Workspace layout — 0xFF-init grids contiguous, then 0x00-init grids contiguous
constexpr size_t OFF_SUB   = 0;                                   // B*3 f32
constexpr size_t OFF_WIN   = align256(OFF_SUB  + (size_t)B*3*4);  // B*41^3 i32   (0xFF)
constexpr size_t SZ_WIN    = (size_t)B*RG*RG*RG*4;
constexpr size_t OFF_SLOT  = align256(OFF_WIN  + SZ_WIN);         // B*40^3 i32   (0xFF)
constexpr size_t SZ_SLOT   = (size_t)B*VOX*4;
constexpr size_t OFF_AFST  = align256(OFF_SLOT + SZ_SLOT);        // B*40^3 u32   (0xFF)
constexpr size_t FF_END    = OFF_AFST + SZ_SLOT;
constexpr size_t OFF_ACNTG = align256(FF_END);                    // B*40^3 i32   (0x00)
constexpr size_t OFF_CNTS  = align256(OFF_ACNTG+ SZ_SLOT);        // B*16 i32     (0x00)
constexpr size_t OFF_BCNT  = align256(OFF_CNTS + (size_t)B*16*4); // 27*B*16 i32  (0x00)
constexpr size_t SZ_BCNT   = (size_t)B*27*16*4;
constexpr size_t Z_END     = OFF_BCNT + SZ_BCNT;
constexpr size_t OFF_OCC   = align256(Z_END);                     // B*MAXOCC i32
constexpr size_t OFF_FEAT  = align256(OFF_OCC  + (size_t)B*MAXOCC*4); // B*MAXOCC*F f32
constexpr size_t OFF_WT    = align256(OFF_FEAT + (size_t)B*MAXOCC*F*4); // 27*F*C f32
constexpr size_t OFF_BG    = align256(OFF_WT   + (size_t)27*F*C*4);     // NBG f32
constexpr size_t OFF_SBUK  = align256(OFF_BG   + (size_t)NBG*4);        // B*27*MAXOCC int2
constexpr size_t OFF_MLST  = align256(OFF_SBUK + (size_t)B*27*MAXOCC*8);// B*MAXACT int2
constexpr size_t OFF_BSUM  = align256(OFF_MLST + (size_t)B*MAXACT*8);   // B*BSR f32
constexpr size_t OFF_FCT   = align256(OFF_BSUM + (size_t)B*BSR*4);      // VOX*C f32
constexpr size_t OFF_END   = OFF_FCT + (size_t)VOX*C*4;

constexpr int WT_BLKS = (27*F*C + 63)/64;
// custom clear segments (both region sizes are multiples of 256 B by construction)
constexpr size_t SZ_FF = FF_END - OFF_WIN;      // 0xFF region bytes
constexpr size_t SZ_Z  = Z_END  - OFF_ACNTG;    // 0x00 region bytes
constexpr size_t NF4 = SZ_FF/16, NZ4 = SZ_Z/16; // uint4 counts
constexpr int CLRF_BLKS = 1024, CLRZ_BLKS = 512;

// ---------------- K1: bbox + conv_w transpose + workspace clear ----------------
__global__ __launch_bounds__(64)
void k_init(const float* __restrict__ pos1, const float* __restrict__ valid1,
            float* __restrict__ sub, const float* __restrict__ conv_w,
            float* __restrict__ Wt, uint4* __restrict__ ff4, uint4* __restrict__ z4) {
    if (blockIdx.x < B) {
        int b = blockIdx.x;
        int t = threadIdx.x;
        float bmax[3] = {-FLT_MAX, -FLT_MAX, -FLT_MAX};
        float bmin[3] = { FLT_MAX,  FLT_MAX,  FLT_MAX};
        for (int n = t; n < N1; n += 64) {
            float v = valid1[b*N1 + n];
            const float* pp = pos1 + ((size_t)b*N1 + n)*3;
            float p0 = pp[0]*v, p1 = pp[1]*v, p2 = pp[2]*v;
            float s = p0 + p1 + p2;
            bool nz = (s == 0.0f);
            float amax = nz ? -10000000000.0f : 0.0f;
            float amin = nz ?  10000000000.0f : 0.0f;
            bmax[0] = fmaxf(bmax[0], p0 + amax);
            bmax[1] = fmaxf(bmax[1], p1 + amax);
            bmax[2] = fmaxf(bmax[2], p2 + amax);
            bmin[0] = fminf(bmin[0], p0 + amin);
            bmin[1] = fminf(bmin[1], p1 + amin);
            bmin[2] = fminf(bmin[2], p2 + amin);
        }
        #pragma unroll
        for (int off = 32; off; off >>= 1) {
            #pragma unroll
            for (int d = 0; d < 3; d++) {
                bmax[d] = fmaxf(bmax[d], __shfl_xor(bmax[d], off));
                bmin[d] = fminf(bmin[d], __shfl_xor(bmin[d], off));
            }
        }
        if (t == 0) {
            #pragma unroll
            for (int d = 0; d < 3; d++)
                sub[b*3 + d] = bmin[d] + (bmax[d] - bmin[d]) / 2.0f;
        }
    } else if (blockIdx.x < B + WT_BLKS) {
        int g = (blockIdx.x - B)*64 + threadIdx.x;
        if (g < 27*F*C) {
            int o = g & (C-1);
            int rest = g >> 7;       // C==128
            int f = rest % F, s = rest / F;
            Wt[g] = conv_w[((size_t)o*F + f)*27 + s];
        }
    } else if (blockIdx.x < B + WT_BLKS + CLRF_BLKS) {
        size_t i0 = (size_t)(blockIdx.x - B - WT_BLKS)*64 + threadIdx.x;
        uint4 v = make_uint4(~0u, ~0u, ~0u, ~0u);
        for (size_t i = i0; i < NF4; i += (size_t)CLRF_BLKS*64) ff4[i] = v;
    } else {
        size_t i0 = (size_t)(blockIdx.x - B - WT_BLKS - CLRF_BLKS)*64 + threadIdx.x;
        uint4 v = make_uint4(0u, 0u, 0u, 0u);
        for (size_t i = i0; i < NZ4; i += (size_t)CLRZ_BLKS*64) z4[i] = v;
    }
}

// helper: compute voxel index for global point n (n<N1 -> pos1 else pos2)
__device__ inline void point_idx(const float* pos1, const float* valid1,
                                 const float* pos2, const float* valid2,
                                 const float* sub, int b, int n,
                                 int& ix, int& iy, int& iz, bool& inb, float& vout) {
    float px, py, pz, v;
    if (n < N1) {
        v = valid1[b*N1 + n];
        const float* p = pos1 + ((size_t)b*N1 + n)*3;
        px = p[0]*v; py = p[1]*v; pz = p[2]*v;
    } else {
        int m = n - N1;
        v = valid2[b*N2 + m];
        const float* p = pos2 + ((size_t)b*N2 + m)*3;
        px = p[0]*v; py = p[1]*v; pz = p[2]*v;
    }
    const float* sb = sub + b*3;
    ix = (int)floorf((px - sb[0] + 10.0f) / 0.5f);
    iy = (int)floorf((py - sb[1] + 10.0f) / 0.5f);
    iz = (int)floorf((pz - sb[2] + 10.0f) / 0.5f);
    inb = (ix >= 0 && ix <= RR-1 && iy >= 0 && iy <= RR-1 && iz >= 0 && iz <= RR-1);
    vout = v;
}

// ---------------- K2: winner scatter (last-write-wins via atomicMax) ----------------
__global__ void k_scatter(const float* __restrict__ pos1, const float* __restrict__ valid1,
                          const float* __restrict__ pos2, const float* __restrict__ valid2,
                          const float* __restrict__ sub, int* __restrict__ winner) {
    int g = blockIdx.x*blockDim.x + threadIdx.x;
    if (g >= B*NP) return;
    int b = g / NP, n = g % NP;
    int ix, iy, iz; bool inb; float v;
    point_idx(pos1, valid1, pos2, valid2, sub, b, n, ix, iy, iz, inb, v);
    int x = inb ? ix : RR, y = inb ? iy : RR, z = inb ? iz : RR;
    int cell = (x*RG + y)*RG + z;
    atomicMax(&winner[(size_t)b*RG*RG*RG + cell], n);
}

// ---------------- K3: claim winners, compact occupied list + features ----------------
__global__ void k_claim(const float* __restrict__ pos1, const float* __restrict__ valid1,
                        const float* __restrict__ pos2, const float* __restrict__ valid2,
                        const float* __restrict__ h1, const float* __restrict__ h2,
                        const float* __restrict__ sub, const int* __restrict__ winner,
                        int* __restrict__ slotGrid, int* __restrict__ counts,
                        int* __restrict__ occCoords, float* __restrict__ feats) {
    int g = blockIdx.x*blockDim.x + threadIdx.x;
    if (g >= B*NP) return;
    int b = g / NP, n = g % NP;
    int ix, iy, iz; bool inb; float v;
    point_idx(pos1, valid1, pos2, valid2, sub, b, n, ix, iy, iz, inb, v);
    if (!inb) return;  // dump cell (40,40,40) is sliced off
    int cell = (ix*RG + iy)*RG + iz;
    if (winner[(size_t)b*RG*RG*RG + cell] != n) return;
    int slot = atomicAdd(&counts[b*16], 1);
    slotGrid[(size_t)b*VOX + (ix*RR + iy)*RR + iz] = slot;
    occCoords[b*MAXOCC + slot] = (ix << 12) | (iy << 6) | iz;
    const float* h = (n < N1) ? (h1 + ((size_t)b*N1 + n)*F)
                              : (h2 + ((size_t)b*N2 + (n - N1))*F);
    float* fo = feats + ((size_t)b*MAXOCC + slot)*F;
    for (int f = 0; f < F; f++) fo[f] = h[f] * v;
}

// ---------------- K4: dilate -> contributor count + deterministic owner (atomicMin) ----------------
__global__ void k_dilate(const int* __restrict__ counts, const int* __restrict__ occCoords,
                         int* __restrict__ actCnt, unsigned* __restrict__ actFirst) {
    int g = blockIdx.x*blockDim.x + threadIdx.x;
    if (g >= B*MAXOCC*27) return;
    int b = g / (MAXOCC*27);
    int rem = g % (MAXOCC*27);
    int sl = rem / 27, k = rem % 27;
    if (sl >= counts[b*16]) return;
    int pc = occCoords[b*MAXOCC + sl];
    int x = pc >> 12, y = (pc >> 6) & 63, z = pc & 63;
    int nx = x + k/9 - 1, ny = y + (k/3)%3 - 1, nz = z + k%3 - 1;
    if (nx < 0 || nx >= RR || ny < 0 || ny >= RR || nz < 0 || nz >= RR) return;
    size_t lin = (size_t)b*VOX + (nx*RR + ny)*RR + nz;
    atomicAdd(&actCnt[lin], 1);
    int sten = (2 - k/9)*9 + ((k/3)%3)*3 + (k%3);
    atomicMin(&actFirst[lin], ((unsigned)sl << 5) | (unsigned)sten);
}

// ---------------- shared compact body ----------------
__device__ inline void compact_body(int g,
               const int* __restrict__ counts, const int* __restrict__ occCoords,
               const int* __restrict__ actCnt, const unsigned* __restrict__ actFirst,
               int* __restrict__ countsW, int* __restrict__ bCnt,
               int2* __restrict__ sBuck, int2* __restrict__ mList, int lane) {
    int bucket = g / PPS;          // b*27 + k
    int s = g % PPS;
    int b = bucket / 27, k = bucket % 27;
    if (b >= B) return;
    int sten = (2 - k/9)*9 + ((k/3)%3)*3 + (k%3);  // wave-uniform (bijection of k)
    bool ownS = false, ownM = false; int pcOut = 0;
    if (s < counts[b*16]) {
        int pc = occCoords[b*MAXOCC + s];
        int x = pc >> 12, y = (pc >> 6) & 63, z = pc & 63;
        int x0 = x + k/9 - 1, y0 = y + (k/3)%3 - 1, z0 = z + k%3 - 1;
        if (x0 >= 0 && x0 < RR && y0 >= 0 && y0 < RR && z0 >= 0 && z0 < RR) {
            size_t lin = (size_t)b*VOX + (x0*RR + y0)*RR + z0;
            unsigned myid = ((unsigned)s << 5) | (unsigned)sten;
            if (actFirst[lin] == myid) {
                pcOut = (x0 << 12) | (y0 << 6) | z0;
                if (actCnt[lin] == 1) ownS = true; else ownM = true;
            }
        }
    }
    unsigned long long mS = __ballot(ownS);
    if (mS != 0ull) {
        int lead = __builtin_ctzll(mS);
        int base = 0;
        if (lane == lead) base = atomicAdd(&bCnt[(b*27 + sten)*16], __popcll(mS));
        base = __shfl(base, lead);
        if (ownS) {
            int rank = __popcll(mS & ((1ull << lane) - 1ull));
            sBuck[((size_t)(b*27 + sten))*MAXOCC + base + rank] = make_int2(pcOut, s);
        }
    }
    unsigned long long mM = __ballot(ownM);
    if (mM != 0ull) {
        int lead = __builtin_ctzll(mM);
        int base = 0;
        if (lane == lead) base = atomicAdd(&countsW[b*16 + 8], __popcll(mM));
        base = __shfl(base, lead);
        if (ownM) {
            int rank = __popcll(mM & ((1ull << lane) - 1ull));
            mList[(size_t)b*MAXACT + base + rank] = make_int2(pcOut, 0);
        }
    }
}

// ---------------- K5: standalone compact (fallback path) ----------------
__global__ __launch_bounds__(256)
void k_compact(const int* __restrict__ counts, const int* __restrict__ occCoords,
               const int* __restrict__ actCnt, const unsigned* __restrict__ actFirst,
               int* __restrict__ countsW, int* __restrict__ bCnt,
               int2* __restrict__ sBuck, int2* __restrict__ mList) {
    int g = blockIdx.x*256 + threadIdx.x;
    compact_body(g, counts, occCoords, actCnt, actFirst, countsW, bCnt, sBuck, mList,
                 threadIdx.x & 63);
}

// ---------------- K6: fused fc_w transpose + background partials + compact ----------------
__global__ __launch_bounds__(256)
void k_fct_compact(const float* __restrict__ fc_w, const float* __restrict__ conv_b,
                   float* __restrict__ fcT, float* __restrict__ bgBlock,
                   const int* __restrict__ counts, const int* __restrict__ occCoords,
                   const int* __restrict__ actCnt, const unsigned* __restrict__ actFirst,
                   int* __restrict__ countsW, int* __restrict__ bCnt,
                   int2* __restrict__ sBuck, int2* __restrict__ mList) {
    if (blockIdx.x < CPB) {
        int g = ((int)blockIdx.y*CPB + blockIdx.x)*256 + threadIdx.x;
        compact_body(g, counts, occCoords, actCnt, actFirst, countsW, bCnt, sBuck, mList,
                     threadIdx.x & 63);
        return;
    }
    __shared__ float tile[16][65];
    __shared__ float sred[16][17];
    __shared__ float sredw[16];
    int v0 = (blockIdx.x - CPB) * 64;  // 1000 v-blocks
    int o0 = blockIdx.y * 16;          // 8 o-blocks (B == C/16)
    int t = threadIdx.x;               // 256
    int tv = t & 63, to = t >> 6;
    #pragma unroll
    for (int oo = 0; oo < 16; oo += 4)
        tile[to + oo][tv] = fc_w[(size_t)(o0 + to + oo)*VOX + v0 + tv];
    __syncthreads();
    int to2 = t & 15, tv2 = t >> 4;
    float s = 0.0f;
    #pragma unroll
    for (int vv = 0; vv < 64; vv += 16) {
        float val = tile[to2][tv2 + vv];
        fcT[(size_t)(v0 + tv2 + vv)*C + o0 + to2] = val;
        s += val;
    }
    sred[to2][tv2] = s;
    __syncthreads();
    if (t < 16) {
        float tot = 0.0f;
        #pragma unroll
        for (int i = 0; i < 16; i++) tot += sred[t][i];
        sredw[t] = fmaxf(conv_b[o0 + t], 0.0f) * tot;
    }
    __syncthreads();
    if (t == 0) {
        float tot = 0.0f;
        #pragma unroll
        for (int i = 0; i < 16; i++) tot += sredw[i];
        bgBlock[blockIdx.y*1000 + (blockIdx.x - CPB)] = tot;
    }
}

// ---------------- K6b: fallback background when fcT doesn't fit ----------------
__global__ __launch_bounds__(256)
void k_bg_fb(const float* __restrict__ fc_w, const float* __restrict__ conv_b,
             float* __restrict__ bgBlock) {
    int o = blockIdx.x;  // 128
    int t = threadIdx.x; // 256
    float s = 0.0f;
    for (int v = t; v < VOX; v += 256) s += fc_w[(size_t)o*VOX + v];
    #pragma unroll
    for (int off = 32; off; off >>= 1) s += __shfl_xor(s, off);
    __shared__ float red4[4];
    if ((t & 63) == 0) red4[t >> 6] = s;
    __syncthreads();
    if (t == 0) bgBlock[o] = fmaxf(conv_b[o], 0.0f) * (red4[0] + red4[1] + red4[2] + red4[3]);
}

// ---------------- K7: singles conv (r7 structure + fcT prefetch, unroll 6) ----------------
__global__ __launch_bounds__(128)
void k_convS(const float* __restrict__ feats, const int* __restrict__ bCnt,
             const int2* __restrict__ sBuck, const float* __restrict__ Wt,
             const float* __restrict__ conv_b, const float* __restrict__ fcT,
             const float* __restrict__ fc_w, int useT, float* __restrict__ bsum) {
    int b = blockIdx.y;
    int sten = blockIdx.x >> 5;
    int chunk = blockIdx.x & 31;
    int t = threadIdx.x;  // 128 = channels
    int idxOut = sten*NCHUNK + chunk;
    int cnt = bCnt[(b*27 + sten)*16];
    int base = chunk*PCHUNK;
    if (base >= cnt) { if (t == 0) bsum[(size_t)b*BSR + idxOut] = 0.0f; return; }
    int rem = min(PCHUNK, cnt - base);

    __shared__ float fLDS[54][20];   // stride 20 floats (80B, 16B-aligned rows)
    __shared__ int   flatS[16];
    __shared__ int   slotS[16];
    __shared__ float red[2];

    if (t < 16) {
        if (t < rem) {
            int2 e = sBuck[((size_t)(b*27 + sten))*MAXOCC + base + t];
            int pc = e.x;
            int x0 = pc >> 12, y0 = (pc >> 6) & 63, z0 = pc & 63;
            flatS[t] = x0*1600 + (RR-1 - y0)*RR + (RR-1 - z0);
            slotS[t] = e.y;
        } else { flatS[t] = 0; slotS[t] = -1; }
    }
    __syncthreads();

    // T14-style prefetch: the 16 scattered fc-weight loads issue NOW so their
    // HBM latency hides under feature staging + the f-loop.
    float wf[16];
    #pragma unroll
    for (int p = 0; p < 16; p++)
        wf[p] = useT ? fcT[(size_t)flatS[p]*C + t]
                     : fc_w[(size_t)t*VOX + flatS[p]];

    for (int idx = t; idx < PCHUNK*F; idx += 128) {
        int p = idx / F, f = idx - p*F;
        int sl = slotS[p];
        fLDS[f][p] = (sl >= 0) ? feats[((size_t)b*MAXOCC + sl)*F + f] : 0.0f;
    }
    __syncthreads();

    const float* wv = Wt + (size_t)sten*F*C + t;
    float acc[16];
    #pragma unroll
    for (int p = 0; p < 16; p++) acc[p] = 0.0f;
    #pragma unroll 6
    for (int f = 0; f < F; f++) {
        float w = wv[(size_t)f*C];
        float4 a = *(const float4*)&fLDS[f][0];
        float4 q = *(const float4*)&fLDS[f][4];
        float4 c = *(const float4*)&fLDS[f][8];
        float4 d = *(const float4*)&fLDS[f][12];
        acc[0]  = fmaf(a.x, w, acc[0]);  acc[1]  = fmaf(a.y, w, acc[1]);
        acc[2]  = fmaf(a.z, w, acc[2]);  acc[3]  = fmaf(a.w, w, acc[3]);
        acc[4]  = fmaf(q.x, w, acc[4]);  acc[5]  = fmaf(q.y, w, acc[5]);
        acc[6]  = fmaf(q.z, w, acc[6]);  acc[7]  = fmaf(q.w, w, acc[7]);
        acc[8]  = fmaf(c.x, w, acc[8]);  acc[9]  = fmaf(c.y, w, acc[9]);
        acc[10] = fmaf(c.z, w, acc[10]); acc[11] = fmaf(c.w, w, acc[11]);
        acc[12] = fmaf(d.x, w, acc[12]); acc[13] = fmaf(d.y, w, acc[13]);
        acc[14] = fmaf(d.z, w, acc[14]); acc[15] = fmaf(d.w, w, acc[15]);
    }
    float cb = conv_b[t];
    float rb = fmaxf(cb, 0.0f);
    float ssum = 0.0f;
    #pragma unroll
    for (int p = 0; p < 16; p++) {
        if (p < rem) {
            float outv = fmaxf(acc[p] + cb, 0.0f) - rb;
            ssum = fmaf(outv, wf[p], ssum);
        }
    }
    #pragma unroll
    for (int off = 32; off; off >>= 1) ssum += __shfl_xor(ssum, off);
    if ((t & 63) == 0) red[t >> 6] = ssum;
    __syncthreads();
    if (t == 0) bsum[(size_t)b*BSR + idxOut] = red[0] + red[1];
}

// ---------------- K8: multi conv — 1 wave/voxel, paired shuffle-broadcast ----------------
__global__ __launch_bounds__(256)
void k_convM(const int* __restrict__ slotGrid, const float* __restrict__ feats,
             const int* __restrict__ counts, const int2* __restrict__ mList,
             const float* __restrict__ Wt, const float* __restrict__ conv_b,
             const float* __restrict__ fcT, const float* __restrict__ fc_w, int useT,
             float* __restrict__ bsum) {
    int b = blockIdx.y;
    int wave = blockIdx.x*4 + (threadIdx.x >> 6);
    int lane = threadIdx.x & 63;
    int cntM = counts[b*16 + 8];
    int nw = gridDim.x*4;
    float cb0 = conv_b[lane], cb1 = conv_b[lane + 64];
    float rb0 = fmaxf(cb0, 0.0f), rb1 = fmaxf(cb1, 0.0f);

    for (int i = wave; i < cntM; i += nw) {
        int pc = mList[(size_t)b*MAXACT + i].x;
        int x0 = pc >> 12, y0 = (pc >> 6) & 63, z0 = pc & 63;
        int flat = x0*1600 + (RR-1 - y0)*RR + (RR-1 - z0);
        float w0, w1;
        if (useT) {
            w0 = fcT[(size_t)flat*C + lane];
            w1 = fcT[(size_t)flat*C + lane + 64];
        } else {
            w0 = fc_w[(size_t)lane*VOX + flat];
            w1 = fc_w[(size_t)(lane + 64)*VOX + flat];
        }
        int sl = -1;
        if (lane < 27) {
            int dp = lane/9, dq = (lane/3)%3, dr = lane%3;
            int nx = x0 + dp - 1, ny = y0 + 1 - dq, nz = z0 + 1 - dr;
            if (nx >= 0 && nx < RR && ny >= 0 && ny < RR && nz >= 0 && nz < RR)
                sl = slotGrid[(size_t)b*VOX + (nx*RR + ny)*RR + nz];
        }
        unsigned long long mask = __ballot(sl >= 0);
        float acc0 = 0.0f, acc1 = 0.0f;
        while (mask) {
            int eA = __builtin_ctzll(mask); mask &= mask - 1;
            int eB = eA;
            bool two = (mask != 0ull);
            if (two) { eB = __builtin_ctzll(mask); mask &= mask - 1; }
            int slA = __shfl(sl, eA);
            int slB = __shfl(sl, eB);
            float v0 = 0.0f, v1 = 0.0f;
            if (lane < F) {
                v0 = feats[((size_t)b*MAXOCC + slA)*F + lane];
                v1 = two ? feats[((size_t)b*MAXOCC + slB)*F + lane] : 0.0f;
            }
            const float* wpA = Wt + (size_t)eA*F*C;
            const float* wpB = Wt + (size_t)eB*F*C;
            #pragma unroll 9
            for (int f = 0; f < F; f++) {
                float fA = __shfl(v0, f);
                float fB = __shfl(v1, f);
                acc0 = fmaf(fA, wpA[f*C + lane],      acc0);
                acc1 = fmaf(fA, wpA[f*C + lane + 64], acc1);
                acc0 = fmaf(fB, wpB[f*C + lane],      acc0);
                acc1 = fmaf(fB, wpB[f*C + lane + 64], acc1);
            }
        }
        float o0 = fmaxf(acc0 + cb0, 0.0f) - rb0;
        float o1 = fmaxf(acc1 + cb1, 0.0f) - rb1;
        float s = fmaf(o0, w0, o1*w1);
        #pragma unroll
        for (int off = 32; off; off >>= 1) s += __shfl_xor(s, off);
        if (lane == 0) bsum[(size_t)b*BSR + 1024 + i] = s;
    }
}

// ---------------- K9: deterministic per-batch reduce + background + sigmoid ----------------
__global__ __launch_bounds__(1024)
void k_reduce(const float* __restrict__ bsum, const float* __restrict__ bgBlock,
              const float* __restrict__ fc_b, const int* __restrict__ counts,
              float* __restrict__ out) {
    int b = blockIdx.x;
    int t = threadIdx.x;  // 1024
    float s = 0.0f;
    for (int i = t; i < 27*NCHUNK; i += 1024) s += bsum[(size_t)b*BSR + i];
    int cntM = counts[b*16 + 8];
    for (int i = t; i < cntM; i += 1024) s += bsum[(size_t)b*BSR + 1024 + i];
    for (int i = t; i < NBG; i += 1024) s += bgBlock[i];
    #pragma unroll
    for (int off = 32; off; off >>= 1) s += __shfl_xor(s, off);
    __shared__ float red[16];
    if ((t & 63) == 0) red[t >> 6] = s;
    __syncthreads();
    if (t == 0) {
        float tot = fc_b[0];
        #pragma unroll
        for (int i = 0; i < 16; i++) tot += red[i];
        out[b] = 1.0f / (1.0f + expf(-tot));
    }
}

extern "C" void kernel_launch(void* const* d_in, const int* in_sizes, int n_in,
                              void* d_out, int out_size, void* d_ws, size_t ws_size,
                              hipStream_t stream) {
    const float* pos1   = (const float*)d_in[0];
    const float* pos2   = (const float*)d_in[1];
    const float* h1     = (const float*)d_in[2];
    const float* h2     = (const float*)d_in[3];
    const float* valid1 = (const float*)d_in[4];
    const float* valid2 = (const float*)d_in[5];
    const float* conv_w = (const float*)d_in[6];
    const float* conv_b = (const float*)d_in[7];
    const float* fc_w   = (const float*)d_in[8];
    const float* fc_b   = (const float*)d_in[9];
    float* out = (float*)d_out;

    char* ws = (char*)d_ws;
    float*    sub      = (float*)   (ws + OFF_SUB);
    int*      winner   = (int*)     (ws + OFF_WIN);
    int*      slotGrid = (int*)     (ws + OFF_SLOT);
    unsigned* actFirst = (unsigned*)(ws + OFF_AFST);
    int*      actCnt   = (int*)     (ws + OFF_ACNTG);
    int*      counts   = (int*)     (ws + OFF_CNTS);
    int*      bCnt     = (int*)     (ws + OFF_BCNT);
    int*      occCoords= (int*)     (ws + OFF_OCC);
    float*    feats    = (float*)   (ws + OFF_FEAT);
    float*    Wt       = (float*)   (ws + OFF_WT);
    float*    bgBlock  = (float*)   (ws + OFF_BG);
    int2*     sBuck    = (int2*)    (ws + OFF_SBUK);
    int2*     mList    = (int2*)    (ws + OFF_MLST);
    float*    bsum     = (float*)   (ws + OFF_BSUM);
    float*    fcT      = (float*)   (ws + OFF_FCT);

    const int useT = (ws_size >= OFF_END) ? 1 : 0;

    // workspace clear is fused into k_init (custom grid-stride clear — the
    // runtime fillBuffer kernel measured 44 us for the same job)
    k_init<<<B + WT_BLKS + CLRF_BLKS + CLRZ_BLKS, 64, 0, stream>>>(
        pos1, valid1, sub, conv_w, Wt,
        (uint4*)(ws + OFF_WIN), (uint4*)(ws + OFF_ACNTG));
    k_scatter<<<(B*NP + 255)/256, 256, 0, stream>>>(pos1, valid1, pos2, valid2, sub, winner);
    k_claim<<<(B*NP + 255)/256, 256, 0, stream>>>(pos1, valid1, pos2, valid2, h1, h2,
                                                  sub, winner, slotGrid, counts, occCoords, feats);
    k_dilate<<<(B*MAXOCC*27 + 255)/256, 256, 0, stream>>>(counts, occCoords, actCnt, actFirst);
    if (useT) {
        k_fct_compact<<<dim3(CPB + VOX/64, B), 256, 0, stream>>>(
            fc_w, conv_b, fcT, bgBlock,
            counts, occCoords, actCnt, actFirst, counts, bCnt, sBuck, mList);
    } else {
        k_compact<<<(B*27*PPS)/256, 256, 0, stream>>>(counts, occCoords, actCnt, actFirst,
                                                      counts, bCnt, sBuck, mList);
        hipMemsetAsync(bgBlock, 0x00, (size_t)NBG*4, stream);
        k_bg_fb<<<C, 256, 0, stream>>>(fc_w, conv_b, bgBlock);
    }
    k_convS<<<dim3(27*NCHUNK, B), 128, 0, stream>>>(feats, bCnt, sBuck, Wt, conv_b,
                                                    fcT, fc_w, useT, bsum);
    k_convM<<<dim3(512, B), 256, 0, stream>>>(slotGrid, feats, counts, mList,
                                              Wt, conv_b, fcT, fc_w, useT, bsum);
    k_reduce<<<B, 1024, 0, stream>>>(bsum, bgBlock, fc_b, counts, out);
}

// Round 16
// 110.590 us; speedup vs baseline: 1.3387x; 1.0498x over previous
//
#include <hip/hip_runtime.h>
#include <float.h>
#include <math.h>

// Problem constants (fixed shapes from setup_inputs)
constexpr int B = 8, N1 = 400, N2 = 64, NP = N1 + N2, F = 54, C = 128;
constexpr int RR = 40;        // lattice size after slicing
constexpr int RG = 41;        // scatter grid (includes dump cell at 40,40,40)
constexpr int VOX = RR*RR*RR; // 64000
constexpr int MAXOCC = NP;            // max occupied voxels per batch
constexpr int MAXACT = NP * 27;       // max multi voxels per batch
constexpr int NBG = (VOX/64) * (C/16);     // 8000 background partials
constexpr int PCHUNK = 16;            // pairs per S-block
constexpr int NCHUNK = 32;            // chunks per (b,sten) bucket
constexpr int SBLK2 = 27*NCHUNK;      // 864 S-blocks per batch
constexpr int MBLK2 = 1024;           // M-blocks per batch (2 waves each)
constexpr int BSR = 16384;            // bsum region per batch (singles [0,864), multi 1024+)
constexpr int PPS = 512;              // padded s-range per (b,k) in k_compact
constexpr int CPB = 54;               // compact blocks per batch (27*512/256)

constexpr size_t align256(size_t x) { return (x + 255) & ~(size_t)255; }

// Workspace layout — 0xFF-init grids contiguous, then 0x00-init grids contiguous
constexpr size_t OFF_SUB   = 0;                                   // B*3 f32
constexpr size_t OFF_WIN   = align256(OFF_SUB  + (size_t)B*3*4);  // B*41^3 i32   (0xFF)
constexpr size_t SZ_WIN    = (size_t)B*RG*RG*RG*4;
constexpr size_t OFF_SLOT  = align256(OFF_WIN  + SZ_WIN);         // B*40^3 i32   (0xFF)
constexpr size_t SZ_SLOT   = (size_t)B*VOX*4;
constexpr size_t OFF_AFST  = align256(OFF_SLOT + SZ_SLOT);        // B*40^3 u32   (0xFF)
constexpr size_t FF_END    = OFF_AFST + SZ_SLOT;
constexpr size_t OFF_ACNTG = align256(FF_END);                    // B*40^3 i32   (0x00)
constexpr size_t OFF_CNTS  = align256(OFF_ACNTG+ SZ_SLOT);        // B*16 i32     (0x00)
constexpr size_t OFF_BCNT  = align256(OFF_CNTS + (size_t)B*16*4); // 27*B*16 i32  (0x00)
constexpr size_t SZ_BCNT   = (size_t)B*27*16*4;
constexpr size_t Z_END     = OFF_BCNT + SZ_BCNT;
constexpr size_t OFF_OCC   = align256(Z_END);                     // B*MAXOCC i32
constexpr size_t OFF_FEAT  = align256(OFF_OCC  + (size_t)B*MAXOCC*4); // B*MAXOCC*F f32
constexpr size_t OFF_WT    = align256(OFF_FEAT + (size_t)B*MAXOCC*F*4); // 27*F*C f32
constexpr size_t OFF_BG    = align256(OFF_WT   + (size_t)27*F*C*4);     // NBG f32
constexpr size_t OFF_SBUK  = align256(OFF_BG   + (size_t)NBG*4);        // B*27*MAXOCC int2
constexpr size_t OFF_MLST  = align256(OFF_SBUK + (size_t)B*27*MAXOCC*8);// B*MAXACT int2
constexpr size_t OFF_BSUM  = align256(OFF_MLST + (size_t)B*MAXACT*8);   // B*BSR f32
constexpr size_t OFF_FCT   = align256(OFF_BSUM + (size_t)B*BSR*4);      // VOX*C f32
constexpr size_t OFF_END   = OFF_FCT + (size_t)VOX*C*4;

constexpr int WT_BLKS = (27*F*C + 63)/64;
// custom clear segments (both region sizes are multiples of 256 B by construction)
constexpr size_t SZ_FF = FF_END - OFF_WIN;      // 0xFF region bytes
constexpr size_t SZ_Z  = Z_END  - OFF_ACNTG;    // 0x00 region bytes
constexpr size_t NF4 = SZ_FF/16, NZ4 = SZ_Z/16; // uint4 counts
constexpr int CLRF_BLKS = 1024, CLRZ_BLKS = 512;

// ---------------- K1: bbox + conv_w transpose + workspace clear ----------------
__global__ __launch_bounds__(64)
void k_init(const float* __restrict__ pos1, const float* __restrict__ valid1,
            float* __restrict__ sub, const float* __restrict__ conv_w,
            float* __restrict__ Wt, uint4* __restrict__ ff4, uint4* __restrict__ z4) {
    if (blockIdx.x < B) {
        int b = blockIdx.x;
        int t = threadIdx.x;
        float bmax[3] = {-FLT_MAX, -FLT_MAX, -FLT_MAX};
        float bmin[3] = { FLT_MAX,  FLT_MAX,  FLT_MAX};
        for (int n = t; n < N1; n += 64) {
            float v = valid1[b*N1 + n];
            const float* pp = pos1 + ((size_t)b*N1 + n)*3;
            float p0 = pp[0]*v, p1 = pp[1]*v, p2 = pp[2]*v;
            float s = p0 + p1 + p2;
            bool nz = (s == 0.0f);
            float amax = nz ? -10000000000.0f : 0.0f;
            float amin = nz ?  10000000000.0f : 0.0f;
            bmax[0] = fmaxf(bmax[0], p0 + amax);
            bmax[1] = fmaxf(bmax[1], p1 + amax);
            bmax[2] = fmaxf(bmax[2], p2 + amax);
            bmin[0] = fminf(bmin[0], p0 + amin);
            bmin[1] = fminf(bmin[1], p1 + amin);
            bmin[2] = fminf(bmin[2], p2 + amin);
        }
        #pragma unroll
        for (int off = 32; off; off >>= 1) {
            #pragma unroll
            for (int d = 0; d < 3; d++) {
                bmax[d] = fmaxf(bmax[d], __shfl_xor(bmax[d], off));
                bmin[d] = fminf(bmin[d], __shfl_xor(bmin[d], off));
            }
        }
        if (t == 0) {
            #pragma unroll
            for (int d = 0; d < 3; d++)
                sub[b*3 + d] = bmin[d] + (bmax[d] - bmin[d]) / 2.0f;
        }
    } else if (blockIdx.x < B + WT_BLKS) {
        int g = (blockIdx.x - B)*64 + threadIdx.x;
        if (g < 27*F*C) {
            int o = g & (C-1);
            int rest = g >> 7;       // C==128
            int f = rest % F, s = rest / F;
            Wt[g] = conv_w[((size_t)o*F + f)*27 + s];
        }
    } else if (blockIdx.x < B + WT_BLKS + CLRF_BLKS) {
        size_t i0 = (size_t)(blockIdx.x - B - WT_BLKS)*64 + threadIdx.x;
        uint4 v = make_uint4(~0u, ~0u, ~0u, ~0u);
        for (size_t i = i0; i < NF4; i += (size_t)CLRF_BLKS*64) ff4[i] = v;
    } else {
        size_t i0 = (size_t)(blockIdx.x - B - WT_BLKS - CLRF_BLKS)*64 + threadIdx.x;
        uint4 v = make_uint4(0u, 0u, 0u, 0u);
        for (size_t i = i0; i < NZ4; i += (size_t)CLRZ_BLKS*64) z4[i] = v;
    }
}

// helper: compute voxel index for global point n (n<N1 -> pos1 else pos2)
__device__ inline void point_idx(const float* pos1, const float* valid1,
                                 const float* pos2, const float* valid2,
                                 const float* sub, int b, int n,
                                 int& ix, int& iy, int& iz, bool& inb, float& vout) {
    float px, py, pz, v;
    if (n < N1) {
        v = valid1[b*N1 + n];
        const float* p = pos1 + ((size_t)b*N1 + n)*3;
        px = p[0]*v; py = p[1]*v; pz = p[2]*v;
    } else {
        int m = n - N1;
        v = valid2[b*N2 + m];
        const float* p = pos2 + ((size_t)b*N2 + m)*3;
        px = p[0]*v; py = p[1]*v; pz = p[2]*v;
    }
    const float* sb = sub + b*3;
    ix = (int)floorf((px - sb[0] + 10.0f) / 0.5f);
    iy = (int)floorf((py - sb[1] + 10.0f) / 0.5f);
    iz = (int)floorf((pz - sb[2] + 10.0f) / 0.5f);
    inb = (ix >= 0 && ix <= RR-1 && iy >= 0 && iy <= RR-1 && iz >= 0 && iz <= RR-1);
    vout = v;
}

// ---------------- K2: winner scatter (last-write-wins via atomicMax) ----------------
__global__ void k_scatter(const float* __restrict__ pos1, const float* __restrict__ valid1,
                          const float* __restrict__ pos2, const float* __restrict__ valid2,
                          const float* __restrict__ sub, int* __restrict__ winner) {
    int g = blockIdx.x*blockDim.x + threadIdx.x;
    if (g >= B*NP) return;
    int b = g / NP, n = g % NP;
    int ix, iy, iz; bool inb; float v;
    point_idx(pos1, valid1, pos2, valid2, sub, b, n, ix, iy, iz, inb, v);
    int x = inb ? ix : RR, y = inb ? iy : RR, z = inb ? iz : RR;
    int cell = (x*RG + y)*RG + z;
    atomicMax(&winner[(size_t)b*RG*RG*RG + cell], n);
}

// ---------------- K3: claim winners, compact occupied list + features ----------------
__global__ void k_claim(const float* __restrict__ pos1, const float* __restrict__ valid1,
                        const float* __restrict__ pos2, const float* __restrict__ valid2,
                        const float* __restrict__ h1, const float* __restrict__ h2,
                        const float* __restrict__ sub, const int* __restrict__ winner,
                        int* __restrict__ slotGrid, int* __restrict__ counts,
                        int* __restrict__ occCoords, float* __restrict__ feats) {
    int g = blockIdx.x*blockDim.x + threadIdx.x;
    if (g >= B*NP) return;
    int b = g / NP, n = g % NP;
    int ix, iy, iz; bool inb; float v;
    point_idx(pos1, valid1, pos2, valid2, sub, b, n, ix, iy, iz, inb, v);
    if (!inb) return;  // dump cell (40,40,40) is sliced off
    int cell = (ix*RG + iy)*RG + iz;
    if (winner[(size_t)b*RG*RG*RG + cell] != n) return;
    int slot = atomicAdd(&counts[b*16], 1);
    slotGrid[(size_t)b*VOX + (ix*RR + iy)*RR + iz] = slot;
    occCoords[b*MAXOCC + slot] = (ix << 12) | (iy << 6) | iz;
    const float* h = (n < N1) ? (h1 + ((size_t)b*N1 + n)*F)
                              : (h2 + ((size_t)b*N2 + (n - N1))*F);
    float* fo = feats + ((size_t)b*MAXOCC + slot)*F;
    for (int f = 0; f < F; f++) fo[f] = h[f] * v;
}

// ---------------- K4: dilate -> contributor count + deterministic owner (atomicMin) ----------------
__global__ void k_dilate(const int* __restrict__ counts, const int* __restrict__ occCoords,
                         int* __restrict__ actCnt, unsigned* __restrict__ actFirst) {
    int g = blockIdx.x*blockDim.x + threadIdx.x;
    if (g >= B*MAXOCC*27) return;
    int b = g / (MAXOCC*27);
    int rem = g % (MAXOCC*27);
    int sl = rem / 27, k = rem % 27;
    if (sl >= counts[b*16]) return;
    int pc = occCoords[b*MAXOCC + sl];
    int x = pc >> 12, y = (pc >> 6) & 63, z = pc & 63;
    int nx = x + k/9 - 1, ny = y + (k/3)%3 - 1, nz = z + k%3 - 1;
    if (nx < 0 || nx >= RR || ny < 0 || ny >= RR || nz < 0 || nz >= RR) return;
    size_t lin = (size_t)b*VOX + (nx*RR + ny)*RR + nz;
    atomicAdd(&actCnt[lin], 1);
    int sten = (2 - k/9)*9 + ((k/3)%3)*3 + (k%3);
    atomicMin(&actFirst[lin], ((unsigned)sl << 5) | (unsigned)sten);
}

// ---------------- shared compact body ----------------
__device__ inline void compact_body(int g,
               const int* __restrict__ counts, const int* __restrict__ occCoords,
               const int* __restrict__ actCnt, const unsigned* __restrict__ actFirst,
               int* __restrict__ countsW, int* __restrict__ bCnt,
               int2* __restrict__ sBuck, int2* __restrict__ mList, int lane) {
    int bucket = g / PPS;          // b*27 + k
    int s = g % PPS;
    int b = bucket / 27, k = bucket % 27;
    if (b >= B) return;
    int sten = (2 - k/9)*9 + ((k/3)%3)*3 + (k%3);  // wave-uniform (bijection of k)
    bool ownS = false, ownM = false; int pcOut = 0;
    if (s < counts[b*16]) {
        int pc = occCoords[b*MAXOCC + s];
        int x = pc >> 12, y = (pc >> 6) & 63, z = pc & 63;
        int x0 = x + k/9 - 1, y0 = y + (k/3)%3 - 1, z0 = z + k%3 - 1;
        if (x0 >= 0 && x0 < RR && y0 >= 0 && y0 < RR && z0 >= 0 && z0 < RR) {
            size_t lin = (size_t)b*VOX + (x0*RR + y0)*RR + z0;
            unsigned myid = ((unsigned)s << 5) | (unsigned)sten;
            if (actFirst[lin] == myid) {
                pcOut = (x0 << 12) | (y0 << 6) | z0;
                if (actCnt[lin] == 1) ownS = true; else ownM = true;
            }
        }
    }
    unsigned long long mS = __ballot(ownS);
    if (mS != 0ull) {
        int lead = __builtin_ctzll(mS);
        int base = 0;
        if (lane == lead) base = atomicAdd(&bCnt[(b*27 + sten)*16], __popcll(mS));
        base = __shfl(base, lead);
        if (ownS) {
            int rank = __popcll(mS & ((1ull << lane) - 1ull));
            sBuck[((size_t)(b*27 + sten))*MAXOCC + base + rank] = make_int2(pcOut, s);
        }
    }
    unsigned long long mM = __ballot(ownM);
    if (mM != 0ull) {
        int lead = __builtin_ctzll(mM);
        int base = 0;
        if (lane == lead) base = atomicAdd(&countsW[b*16 + 8], __popcll(mM));
        base = __shfl(base, lead);
        if (ownM) {
            int rank = __popcll(mM & ((1ull << lane) - 1ull));
            mList[(size_t)b*MAXACT + base + rank] = make_int2(pcOut, 0);
        }
    }
}

// ---------------- K5: standalone compact (fallback path) ----------------
__global__ __launch_bounds__(256)
void k_compact(const int* __restrict__ counts, const int* __restrict__ occCoords,
               const int* __restrict__ actCnt, const unsigned* __restrict__ actFirst,
               int* __restrict__ countsW, int* __restrict__ bCnt,
               int2* __restrict__ sBuck, int2* __restrict__ mList) {
    int g = blockIdx.x*256 + threadIdx.x;
    compact_body(g, counts, occCoords, actCnt, actFirst, countsW, bCnt, sBuck, mList,
                 threadIdx.x & 63);
}

// ---------------- K6: fused fc_w transpose + background partials + compact ----------------
__global__ __launch_bounds__(256)
void k_fct_compact(const float* __restrict__ fc_w, const float* __restrict__ conv_b,
                   float* __restrict__ fcT, float* __restrict__ bgBlock,
                   const int* __restrict__ counts, const int* __restrict__ occCoords,
                   const int* __restrict__ actCnt, const unsigned* __restrict__ actFirst,
                   int* __restrict__ countsW, int* __restrict__ bCnt,
                   int2* __restrict__ sBuck, int2* __restrict__ mList) {
    if (blockIdx.x < CPB) {
        int g = ((int)blockIdx.y*CPB + blockIdx.x)*256 + threadIdx.x;
        compact_body(g, counts, occCoords, actCnt, actFirst, countsW, bCnt, sBuck, mList,
                     threadIdx.x & 63);
        return;
    }
    __shared__ float tile[16][65];
    __shared__ float sred[16][17];
    __shared__ float sredw[16];
    int v0 = (blockIdx.x - CPB) * 64;  // 1000 v-blocks
    int o0 = blockIdx.y * 16;          // 8 o-blocks (B == C/16)
    int t = threadIdx.x;               // 256
    int tv = t & 63, to = t >> 6;
    #pragma unroll
    for (int oo = 0; oo < 16; oo += 4)
        tile[to + oo][tv] = fc_w[(size_t)(o0 + to + oo)*VOX + v0 + tv];
    __syncthreads();
    int to2 = t & 15, tv2 = t >> 4;
    float s = 0.0f;
    #pragma unroll
    for (int vv = 0; vv < 64; vv += 16) {
        float val = tile[to2][tv2 + vv];
        fcT[(size_t)(v0 + tv2 + vv)*C + o0 + to2] = val;
        s += val;
    }
    sred[to2][tv2] = s;
    __syncthreads();
    if (t < 16) {
        float tot = 0.0f;
        #pragma unroll
        for (int i = 0; i < 16; i++) tot += sred[t][i];
        sredw[t] = fmaxf(conv_b[o0 + t], 0.0f) * tot;
    }
    __syncthreads();
    if (t == 0) {
        float tot = 0.0f;
        #pragma unroll
        for (int i = 0; i < 16; i++) tot += sredw[i];
        bgBlock[blockIdx.y*1000 + (blockIdx.x - CPB)] = tot;
    }
}

// ---------------- K6b: fallback background when fcT doesn't fit ----------------
__global__ __launch_bounds__(256)
void k_bg_fb(const float* __restrict__ fc_w, const float* __restrict__ conv_b,
             float* __restrict__ bgBlock) {
    int o = blockIdx.x;  // 128
    int t = threadIdx.x; // 256
    float s = 0.0f;
    for (int v = t; v < VOX; v += 256) s += fc_w[(size_t)o*VOX + v];
    #pragma unroll
    for (int off = 32; off; off >>= 1) s += __shfl_xor(s, off);
    __shared__ float red4[4];
    if ((t & 63) == 0) red4[t >> 6] = s;
    __syncthreads();
    if (t == 0) bgBlock[o] = fmaxf(conv_b[o], 0.0f) * (red4[0] + red4[1] + red4[2] + red4[3]);
}

// ---------------- K7: fused conv — S path (x<SBLK2, r14 body) + M path (2 waves) ----------------
__global__ __launch_bounds__(128)
void k_conv(const int* __restrict__ slotGrid, const float* __restrict__ feats,
            const int* __restrict__ counts, const int* __restrict__ bCnt,
            const int2* __restrict__ sBuck, const int2* __restrict__ mList,
            const float* __restrict__ Wt, const float* __restrict__ conv_b,
            const float* __restrict__ fcT, const float* __restrict__ fc_w, int useT,
            float* __restrict__ bsum) {
    int b = blockIdx.y;
    int t = threadIdx.x;

    __shared__ float fLDS[54][20];   // stride 20 floats (80B, 16B-aligned rows)
    __shared__ int   flatS[16];
    __shared__ int   slotS[16];
    __shared__ float red[2];

    if (blockIdx.x < SBLK2) {
        // ================= singles path (r14 convS verbatim) =================
        int sten = blockIdx.x >> 5;
        int chunk = blockIdx.x & 31;
        int idxOut = sten*NCHUNK + chunk;
        int cnt = bCnt[(b*27 + sten)*16];
        int base = chunk*PCHUNK;
        if (base >= cnt) { if (t == 0) bsum[(size_t)b*BSR + idxOut] = 0.0f; return; }
        int rem = min(PCHUNK, cnt - base);

        if (t < 16) {
            if (t < rem) {
                int2 e = sBuck[((size_t)(b*27 + sten))*MAXOCC + base + t];
                int pc = e.x;
                int x0 = pc >> 12, y0 = (pc >> 6) & 63, z0 = pc & 63;
                flatS[t] = x0*1600 + (RR-1 - y0)*RR + (RR-1 - z0);
                slotS[t] = e.y;
            } else { flatS[t] = 0; slotS[t] = -1; }
        }
        __syncthreads();

        // T14-style prefetch: scattered fc-weight loads issue NOW; latency hides
        // under feature staging + the f-loop.
        float wf[16];
        #pragma unroll
        for (int p = 0; p < 16; p++)
            wf[p] = useT ? fcT[(size_t)flatS[p]*C + t]
                         : fc_w[(size_t)t*VOX + flatS[p]];

        for (int idx = t; idx < PCHUNK*F; idx += 128) {
            int p = idx / F, f = idx - p*F;
            int sl = slotS[p];
            fLDS[f][p] = (sl >= 0) ? feats[((size_t)b*MAXOCC + sl)*F + f] : 0.0f;
        }
        __syncthreads();

        const float* wv = Wt + (size_t)sten*F*C + t;
        float acc[16];
        #pragma unroll
        for (int p = 0; p < 16; p++) acc[p] = 0.0f;
        #pragma unroll 3
        for (int f = 0; f < F; f++) {
            float w = wv[(size_t)f*C];
            float4 a = *(const float4*)&fLDS[f][0];
            float4 q = *(const float4*)&fLDS[f][4];
            float4 c = *(const float4*)&fLDS[f][8];
            float4 d = *(const float4*)&fLDS[f][12];
            acc[0]  = fmaf(a.x, w, acc[0]);  acc[1]  = fmaf(a.y, w, acc[1]);
            acc[2]  = fmaf(a.z, w, acc[2]);  acc[3]  = fmaf(a.w, w, acc[3]);
            acc[4]  = fmaf(q.x, w, acc[4]);  acc[5]  = fmaf(q.y, w, acc[5]);
            acc[6]  = fmaf(q.z, w, acc[6]);  acc[7]  = fmaf(q.w, w, acc[7]);
            acc[8]  = fmaf(c.x, w, acc[8]);  acc[9]  = fmaf(c.y, w, acc[9]);
            acc[10] = fmaf(c.z, w, acc[10]); acc[11] = fmaf(c.w, w, acc[11]);
            acc[12] = fmaf(d.x, w, acc[12]); acc[13] = fmaf(d.y, w, acc[13]);
            acc[14] = fmaf(d.z, w, acc[14]); acc[15] = fmaf(d.w, w, acc[15]);
        }
        float cb = conv_b[t];
        float rb = fmaxf(cb, 0.0f);
        float ssum = 0.0f;
        #pragma unroll
        for (int p = 0; p < 16; p++) {
            if (p < rem) {
                float outv = fmaxf(acc[p] + cb, 0.0f) - rb;
                ssum = fmaf(outv, wf[p], ssum);
            }
        }
        #pragma unroll
        for (int off = 32; off; off >>= 1) ssum += __shfl_xor(ssum, off);
        if ((t & 63) == 0) red[t >> 6] = ssum;
        __syncthreads();
        if (t == 0) bsum[(size_t)b*BSR + idxOut] = red[0] + red[1];
        return;
    }

    // ================= multi path (r14 convM body, 2 waves/block) =================
    int wave = (blockIdx.x - SBLK2)*2 + (t >> 6);
    int lane = t & 63;
    int cntM = counts[b*16 + 8];
    int nw = MBLK2*2;
    float cb0 = conv_b[lane], cb1 = conv_b[lane + 64];
    float rb0 = fmaxf(cb0, 0.0f), rb1 = fmaxf(cb1, 0.0f);

    for (int i = wave; i < cntM; i += nw) {
        int pc = mList[(size_t)b*MAXACT + i].x;
        int x0 = pc >> 12, y0 = (pc >> 6) & 63, z0 = pc & 63;
        int flat = x0*1600 + (RR-1 - y0)*RR + (RR-1 - z0);
        float w0, w1;
        if (useT) {
            w0 = fcT[(size_t)flat*C + lane];
            w1 = fcT[(size_t)flat*C + lane + 64];
        } else {
            w0 = fc_w[(size_t)lane*VOX + flat];
            w1 = fc_w[(size_t)(lane + 64)*VOX + flat];
        }
        int sl = -1;
        if (lane < 27) {
            int dp = lane/9, dq = (lane/3)%3, dr = lane%3;
            int nx = x0 + dp - 1, ny = y0 + 1 - dq, nz = z0 + 1 - dr;
            if (nx >= 0 && nx < RR && ny >= 0 && ny < RR && nz >= 0 && nz < RR)
                sl = slotGrid[(size_t)b*VOX + (nx*RR + ny)*RR + nz];
        }
        unsigned long long mask = __ballot(sl >= 0);
        float acc0 = 0.0f, acc1 = 0.0f;
        while (mask) {
            int eA = __builtin_ctzll(mask); mask &= mask - 1;
            int eB = eA;
            bool two = (mask != 0ull);
            if (two) { eB = __builtin_ctzll(mask); mask &= mask - 1; }
            int slA = __shfl(sl, eA);
            int slB = __shfl(sl, eB);
            float v0 = 0.0f, v1 = 0.0f;
            if (lane < F) {
                v0 = feats[((size_t)b*MAXOCC + slA)*F + lane];
                v1 = two ? feats[((size_t)b*MAXOCC + slB)*F + lane] : 0.0f;
            }
            const float* wpA = Wt + (size_t)eA*F*C;
            const float* wpB = Wt + (size_t)eB*F*C;
            #pragma unroll 9
            for (int f = 0; f < F; f++) {
                float fA = __shfl(v0, f);
                float fB = __shfl(v1, f);
                acc0 = fmaf(fA, wpA[f*C + lane],      acc0);
                acc1 = fmaf(fA, wpA[f*C + lane + 64], acc1);
                acc0 = fmaf(fB, wpB[f*C + lane],      acc0);
                acc1 = fmaf(fB, wpB[f*C + lane + 64], acc1);
            }
        }
        float o0 = fmaxf(acc0 + cb0, 0.0f) - rb0;
        float o1 = fmaxf(acc1 + cb1, 0.0f) - rb1;
        float s = fmaf(o0, w0, o1*w1);
        #pragma unroll
        for (int off = 32; off; off >>= 1) s += __shfl_xor(s, off);
        if (lane == 0) bsum[(size_t)b*BSR + 1024 + i] = s;
    }
}

// ---------------- K9: deterministic per-batch reduce + background + sigmoid ----------------
__global__ __launch_bounds__(1024)
void k_reduce(const float* __restrict__ bsum, const float* __restrict__ bgBlock,
              const float* __restrict__ fc_b, const int* __restrict__ counts,
              float* __restrict__ out) {
    int b = blockIdx.x;
    int t = threadIdx.x;  // 1024
    float s = 0.0f;
    for (int i = t; i < 27*NCHUNK; i += 1024) s += bsum[(size_t)b*BSR + i];
    int cntM = counts[b*16 + 8];
    for (int i = t; i < cntM; i += 1024) s += bsum[(size_t)b*BSR + 1024 + i];
    for (int i = t; i < NBG; i += 1024) s += bgBlock[i];
    #pragma unroll
    for (int off = 32; off; off >>= 1) s += __shfl_xor(s, off);
    __shared__ float red[16];
    if ((t & 63) == 0) red[t >> 6] = s;
    __syncthreads();
    if (t == 0) {
        float tot = fc_b[0];
        #pragma unroll
        for (int i = 0; i < 16; i++) tot += red[i];
        out[b] = 1.0f / (1.0f + expf(-tot));
    }
}

extern "C" void kernel_launch(void* const* d_in, const int* in_sizes, int n_in,
                              void* d_out, int out_size, void* d_ws, size_t ws_size,
                              hipStream_t stream) {
    const float* pos1   = (const float*)d_in[0];
    const float* pos2   = (const float*)d_in[1];
    const float* h1     = (const float*)d_in[2];
    const float* h2     = (const float*)d_in[3];
    const float* valid1 = (const float*)d_in[4];
    const float* valid2 = (const float*)d_in[5];
    const float* conv_w = (const float*)d_in[6];
    const float* conv_b = (const float*)d_in[7];
    const float* fc_w   = (const float*)d_in[8];
    const float* fc_b   = (const float*)d_in[9];
    float* out = (float*)d_out;

    char* ws = (char*)d_ws;
    float*    sub      = (float*)   (ws + OFF_SUB);
    int*      winner   = (int*)     (ws + OFF_WIN);
    int*      slotGrid = (int*)     (ws + OFF_SLOT);
    unsigned* actFirst = (unsigned*)(ws + OFF_AFST);
    int*      actCnt   = (int*)     (ws + OFF_ACNTG);
    int*      counts   = (int*)     (ws + OFF_CNTS);
    int*      bCnt     = (int*)     (ws + OFF_BCNT);
    int*      occCoords= (int*)     (ws + OFF_OCC);
    float*    feats    = (float*)   (ws + OFF_FEAT);
    float*    Wt       = (float*)   (ws + OFF_WT);
    float*    bgBlock  = (float*)   (ws + OFF_BG);
    int2*     sBuck    = (int2*)    (ws + OFF_SBUK);
    int2*     mList    = (int2*)    (ws + OFF_MLST);
    float*    bsum     = (float*)   (ws + OFF_BSUM);
    float*    fcT      = (float*)   (ws + OFF_FCT);

    const int useT = (ws_size >= OFF_END) ? 1 : 0;

    // workspace clear fused into k_init (runtime fillBuffer measured 44 us for this)
    k_init<<<B + WT_BLKS + CLRF_BLKS + CLRZ_BLKS, 64, 0, stream>>>(
        pos1, valid1, sub, conv_w, Wt,
        (uint4*)(ws + OFF_WIN), (uint4*)(ws + OFF_ACNTG));
    k_scatter<<<(B*NP + 255)/256, 256, 0, stream>>>(pos1, valid1, pos2, valid2, sub, winner);
    k_claim<<<(B*NP + 255)/256, 256, 0, stream>>>(pos1, valid1, pos2, valid2, h1, h2,
                                                  sub, winner, slotGrid, counts, occCoords, feats);
    k_dilate<<<(B*MAXOCC*27 + 255)/256, 256, 0, stream>>>(counts, occCoords, actCnt, actFirst);
    if (useT) {
        k_fct_compact<<<dim3(CPB + VOX/64, B), 256, 0, stream>>>(
            fc_w, conv_b, fcT, bgBlock,
            counts, occCoords, actCnt, actFirst, counts, bCnt, sBuck, mList);
    } else {
        k_compact<<<(B*27*PPS)/256, 256, 0, stream>>>(counts, occCoords, actCnt, actFirst,
                                                      counts, bCnt, sBuck, mList);
        hipMemsetAsync(bgBlock, 0x00, (size_t)NBG*4, stream);
        k_bg_fb<<<C, 256, 0, stream>>>(fc_w, conv_b, bgBlock);
    }
    k_conv<<<dim3(SBLK2 + MBLK2, B), 128, 0, stream>>>(slotGrid, feats, counts, bCnt,
                                                       sBuck, mList, Wt, conv_b,
                                                       fcT, fc_w, useT, bsum);
    k_reduce<<<B, 1024, 0, stream>>>(bsum, bgBlock, fc_b, counts, out);
}